// Round 4
// baseline (1956.500 us; speedup 1.0000x reference)
//
#include <hip/hip_runtime.h>
#include <cmath>

// DynamicReductionNetwork forward on MI355X. All f32 (no fp32 MFMA -> vector ALU).
// input MLP -> kNN16 -> EdgeConv -> graclus -> maxpool -> kNN16 -> EdgeConv -> global max -> MLP.
// EdgeConv identity: message at dst i from source s (fwd or rev, deduped) = MLP2(elu(wb[i]+vb[s])),
// summed over the undirected neighbor set K|KT. One edge list serves conv AND graclus.
// Graclus: candidates pre-sorted desc by (w<<32|~j) -> matching picks FIRST valid lane via ballot
// (no shfl max-reduce chain; R3 profile showed 940 cyc/step, mostly 12 dependent u64 shfls).

#define DEVI __device__ __forceinline__
constexpr int B_   = 32;
constexpr int N_   = 1024;
constexpr int NN   = B_ * N_;    // 32768 nodes
constexpr int NCH  = 8;          // knn column chunks
constexpr int CHW  = 128;        // columns per chunk
constexpr int ECAP = 128;        // edge-list cap per node (deg = 16 + in-deg)

#define INFF (__builtin_huge_valf())

DEVI float elu_(float x)  { return x > 0.f ? x : expm1f(x); }          // exact-ish (cheap kernels)
DEVI float eluf(float x)  { return x > 0.f ? x : __expf(x) - 1.f; }    // fast (conv hot loop)

// ---------------------------------------------------------------- input MLP
__global__ __launch_bounds__(256) void k_input(
    const float* __restrict__ x, const float* __restrict__ nrm,
    const float* __restrict__ w1, const float* __restrict__ b1,
    const float* __restrict__ w2, const float* __restrict__ b2,
    const float* __restrict__ w3, const float* __restrict__ b3,
    float* __restrict__ h0, float* __restrict__ x2a)
{
  __shared__ float s1[128], sb1[32], s2[2048], sb2[64], s3[4096], sb3[64];
  int tid = threadIdx.x;
  for (int t = tid; t < 128; t += 256) s1[t] = w1[t];
  if (tid < 32) sb1[tid] = b1[tid];
  for (int t = tid; t < 2048; t += 256) s2[t] = w2[t];
  if (tid < 64) sb2[tid] = b2[tid];
  for (int t = tid; t < 4096; t += 256) s3[t] = w3[t];
  if (tid < 64) sb3[tid] = b3[tid];
  __syncthreads();
  int n = blockIdx.x * 256 + tid;
  float xi[4];
#pragma unroll
  for (int d = 0; d < 4; d++) xi[d] = x[n * 4 + d] * nrm[d];
  float a1[32];
#pragma unroll
  for (int c = 0; c < 32; c++) {
    float a = sb1[c];
#pragma unroll
    for (int d = 0; d < 4; d++) a += xi[d] * s1[d * 32 + c];
    a1[c] = elu_(a);
  }
  float a2[64];
#pragma unroll
  for (int c = 0; c < 64; c++) {
    float a = sb2[c];
#pragma unroll
    for (int d = 0; d < 32; d++) a += a1[d] * s2[d * 64 + c];
    a2[c] = elu_(a);
  }
  float ss = 0.f;
#pragma unroll
  for (int c = 0; c < 64; c++) {
    float a = sb3[c];
#pragma unroll
    for (int d = 0; d < 64; d++) a += a2[d] * s3[d * 64 + c];
    a = elu_(a);
    h0[n * 64 + c] = a;
    ss += a * a;
  }
  x2a[n] = ss;
}

// ---------------------------------------------------------------- kNN partials
// per (graph, 256-row tile, 128-col chunk): per-thread sorted top-16 (d2 asc, tie -> smaller j).
__global__ __launch_bounds__(256) void k_knn(
    const float4* __restrict__ X4, const float* __restrict__ X2,
    const unsigned* __restrict__ vbits, const int* __restrict__ vrows,
    float* __restrict__ pd, unsigned short* __restrict__ pix)
{
  __shared__ float xs[CHW * 64];
  __shared__ float xs2[CHW];
  __shared__ unsigned vm[32];
  int bid = blockIdx.x;
  int swz = (bid & 7) * 128 + (bid >> 3);   // XCD swizzle (1024 blocks, %8==0 -> bijective)
  int b  = swz >> 5;
  int rt = (swz >> 3) & 3;
  int ch = swz & 7;
  int tid = threadIdx.x;
  int j0 = ch * CHW;
  for (int t = tid; t < CHW * 16; t += 256) {
    int r = t >> 4, q = t & 15;
    float4 v = X4[(b * N_ + j0 + r) * 16 + q];
    *reinterpret_cast<float4*>(&xs[r * 64 + q * 4]) = v;
  }
  for (int t = tid; t < CHW; t += 256) xs2[t] = X2[b * N_ + j0 + t];
  for (int t = tid; t < 32; t += 256) vm[t] = vbits ? vbits[b * 32 + t] : 0xFFFFFFFFu;
  __syncthreads();
  int i = rt * 256 + tid;
  int gi = b * N_ + i;
  if (vrows && !vrows[gi]) return;
  float4 xi4[16];
#pragma unroll
  for (int q = 0; q < 16; q++) xi4[q] = X4[gi * 16 + q];
  float x2i = X2[gi];
  float topd[16]; int topi[16];
#pragma unroll
  for (int q = 0; q < 16; q++) { topd[q] = INFF; topi[q] = 0xFFFF; }
  for (int jj = 0; jj < CHW; ++jj) {
    int j = j0 + jj;
    if (j == i) continue;
    if (!((vm[j >> 5] >> (j & 31)) & 1u)) continue;
    const float4* xr = reinterpret_cast<const float4*>(&xs[jj * 64]);  // b128, uniform addr -> broadcast
    float dot = 0.f;
#pragma unroll
    for (int q = 0; q < 16; q++) {
      float4 v = xr[q];
      dot += xi4[q].x * v.x + xi4[q].y * v.y + xi4[q].z * v.z + xi4[q].w * v.w;
    }
    float d2 = fmaxf(x2i + xs2[jj] - 2.f * dot, 0.f);
    if (d2 < topd[15]) {            // strict: equal keeps earlier (smaller j)
      topd[15] = d2; topi[15] = j;
#pragma unroll
      for (int p = 15; p > 0; --p) {
        if (topd[p] < topd[p - 1]) {
          float td = topd[p]; topd[p] = topd[p - 1]; topd[p - 1] = td;
          int   ti = topi[p]; topi[p] = topi[p - 1]; topi[p - 1] = ti;
        }
      }
    }
  }
  size_t base = ((size_t)gi * NCH + ch) * 16;
#pragma unroll
  for (int q = 0; q < 16; q++) { pd[base + q] = topd[q]; pix[base + q] = (unsigned short)topi[q]; }
}

// ---------------------------------------------------------------- kNN merge
// top-16 over 8 sorted partials; writes dense row bitmask K and transposed KT (atomicOr, pre-zeroed).
__global__ __launch_bounds__(64) void k_merge(
    const float* __restrict__ pd, const unsigned short* __restrict__ pix,
    const int* __restrict__ vrows,
    unsigned* __restrict__ Kb, unsigned* __restrict__ KTb)
{
  __shared__ unsigned lbm[64][33];   // 8.4 KB; per-thread row, no cross-thread use
  int tid = threadIdx.x;
  int gi = blockIdx.x * 64 + tid;
  int b = gi >> 10, i = gi & 1023;
  if (vrows && !vrows[gi]) return;
#pragma unroll
  for (int w = 0; w < 32; w++) lbm[tid][w] = 0u;
  float topd[16]; int topi[16];
#pragma unroll
  for (int q = 0; q < 16; q++) { topd[q] = INFF; topi[q] = 0; }
  for (int s = 0; s < NCH; ++s) {
    size_t base = ((size_t)gi * NCH + s) * 16;
#pragma unroll 1
    for (int q = 0; q < 16; q++) {
      float d = pd[base + q];
      if (!(d < topd[15])) break;   // partial ascending -> rest rejected too
      topd[15] = d; topi[15] = pix[base + q];
#pragma unroll
      for (int p = 15; p > 0; --p) {
        if (topd[p] < topd[p - 1]) {
          float td = topd[p]; topd[p] = topd[p - 1]; topd[p - 1] = td;
          int   ti = topi[p]; topi[p] = topi[p - 1]; topi[p - 1] = ti;
        }
      }
    }
  }
#pragma unroll
  for (int q = 0; q < 16; q++) {
    int j = topi[q];
    lbm[tid][j >> 5] |= (1u << (j & 31));
    atomicOr(&KTb[((size_t)b * N_ + j) * 32 + (i >> 5)], 1u << (i & 31));
  }
#pragma unroll
  for (int w = 0; w < 32; w++) Kb[(size_t)gi * 32 + w] = lbm[tid][w];
}

// ---------------------------------------------------------------- edge list (undirected K|KT row)
__global__ __launch_bounds__(256) void k_elist(
    const unsigned* __restrict__ Kb, const unsigned* __restrict__ KTb,
    unsigned short* __restrict__ E, int* __restrict__ ecnt, float* __restrict__ invdeg)
{
  int gi = blockIdx.x * 256 + threadIdx.x;
  unsigned short* e = E + (size_t)gi * ECAP;
  int n = 0;
  for (int w = 0; w < 32; w++) {
    unsigned m = Kb[(size_t)gi * 32 + w] | KTb[(size_t)gi * 32 + w];
    while (m) {
      int bit = __ffs(m) - 1; m &= m - 1;
      if (n < ECAP) e[n] = (unsigned short)(w * 32 + bit);
      n++;
    }
  }
  ecnt[gi] = n < ECAP ? n : ECAP;
  if (invdeg) invdeg[gi] = 1.f / (float)n;   // true degree (matches A.sum(-1))
}

// ---------------------------------------------------------------- edge MLP precompute
// wb = x@(W1[:64]-W1[64:]) + b1 ; vb = x@W1[64:]  (per-edge layer1 = wb_dst + vb_src)
__global__ __launch_bounds__(256) void k_uv(
    const float* __restrict__ X, const float* __restrict__ W1, const float* __restrict__ b1,
    float* __restrict__ wb, float* __restrict__ vb)
{
  __shared__ float wc[64 * 96], wv[64 * 96];
  int tid = threadIdx.x;
  for (int t = tid; t < 64 * 96; t += 256) {
    int d = t / 96, c = t - d * 96;
    float hv = W1[(d + 64) * 96 + c];
    wv[t] = hv;
    wc[t] = W1[d * 96 + c] - hv;
  }
  __syncthreads();
  int n = blockIdx.x * 256 + tid;
  float xi[64];
#pragma unroll
  for (int q = 0; q < 16; q++) {
    float4 v = reinterpret_cast<const float4*>(X)[n * 16 + q];
    xi[q * 4] = v.x; xi[q * 4 + 1] = v.y; xi[q * 4 + 2] = v.z; xi[q * 4 + 3] = v.w;
  }
#pragma unroll 1
  for (int c4 = 0; c4 < 24; c4++) {
    float aw0 = b1[c4 * 4 + 0], aw1 = b1[c4 * 4 + 1], aw2 = b1[c4 * 4 + 2], aw3 = b1[c4 * 4 + 3];
    float av0 = 0.f, av1 = 0.f, av2 = 0.f, av3 = 0.f;
#pragma unroll
    for (int d = 0; d < 64; d++) {
      float4 c = *reinterpret_cast<const float4*>(&wc[d * 96 + c4 * 4]);
      float4 v = *reinterpret_cast<const float4*>(&wv[d * 96 + c4 * 4]);
      float xd = xi[d];
      aw0 += xd * c.x; aw1 += xd * c.y; aw2 += xd * c.z; aw3 += xd * c.w;
      av0 += xd * v.x; av1 += xd * v.y; av2 += xd * v.z; av3 += xd * v.w;
    }
    wb[(size_t)n * 96 + c4 * 4 + 0] = aw0; wb[(size_t)n * 96 + c4 * 4 + 1] = aw1;
    wb[(size_t)n * 96 + c4 * 4 + 2] = aw2; wb[(size_t)n * 96 + c4 * 4 + 3] = aw3;
    vb[(size_t)n * 96 + c4 * 4 + 0] = av0; vb[(size_t)n * 96 + c4 * 4 + 1] = av1;
    vb[(size_t)n * 96 + c4 * 4 + 2] = av2; vb[(size_t)n * 96 + c4 * 4 + 3] = av3;
  }
}

// ---------------------------------------------------------------- EdgeConv
// 4 lanes per dst, each owns a 16-wide output slice; all lanes iterate the same
// edge list (uniform trip count); edge-pair unroll shares each w2s LDS read across 8 FMAs.
__global__ __launch_bounds__(256) void k_conv(
    const float* __restrict__ wbuf, const float* __restrict__ vbuf,
    const unsigned short* __restrict__ E, const int* __restrict__ ecnt,
    const int* __restrict__ vrows,
    const float* __restrict__ W2, const float* __restrict__ b2,
    float* __restrict__ out, float* __restrict__ x2out)
{
  __shared__ float w2s[96 * 64];
  __shared__ float b2s[64];
  __shared__ float wds[64 * 100];   // pad 100: dl*100 stride -> 2-way banks (free per m136)
  int tid = threadIdx.x;
  int bid = blockIdx.x;
  int swz = (bid & 7) * 64 + (bid >> 3);   // XCD swizzle: each XCD -> 4 contiguous graphs
  int dst0 = swz * 64;
  for (int t = tid; t < 96 * 64; t += 256) w2s[t] = W2[t];
  if (tid < 64) b2s[tid] = b2[tid];
  for (int t = tid; t < 64 * 96; t += 256) {
    int l = t / 96, c = t - l * 96;
    wds[l * 100 + c] = wbuf[(size_t)(dst0 + l) * 96 + c];
  }
  __syncthreads();
  int dl = tid >> 2, p = tid & 3;
  int dst = dst0 + dl;
  if (vrows && !vrows[dst]) return;   // quad-uniform
  int cnt = ecnt[dst];
  const unsigned short* e = E + (size_t)dst * ECAP;
  int gb = dst & ~(N_ - 1);
  float agg[16];
#pragma unroll
  for (int o = 0; o < 16; o++) agg[o] = 0.f;

#pragma unroll 1
  for (int k = 0; k < cnt; k += 2) {
    bool hasB = (k + 1 < cnt);
    int sA = gb + e[k];
    int sB = hasB ? gb + e[k + 1] : sA;
    const float4* vA = reinterpret_cast<const float4*>(vbuf + (size_t)sA * 96);
    const float4* vB = reinterpret_cast<const float4*>(vbuf + (size_t)sB * 96);
    float sa[16], sb_[16];
#pragma unroll
    for (int o = 0; o < 16; o++) { sa[o] = b2s[p * 16 + o]; sb_[o] = sa[o]; }
#pragma unroll 1
    for (int c4 = 0; c4 < 24; c4++) {
      float4 wv = *reinterpret_cast<const float4*>(&wds[dl * 100 + c4 * 4]);
      float4 a4 = vA[c4];
      float4 b4 = vB[c4];
      float tA0 = eluf(wv.x + a4.x), tA1 = eluf(wv.y + a4.y),
            tA2 = eluf(wv.z + a4.z), tA3 = eluf(wv.w + a4.w);
      float tB0 = eluf(wv.x + b4.x), tB1 = eluf(wv.y + b4.y),
            tB2 = eluf(wv.z + b4.z), tB3 = eluf(wv.w + b4.w);
      const float* wr = &w2s[(c4 * 4) * 64 + p * 16];
#pragma unroll
      for (int o4 = 0; o4 < 4; o4++) {
        float4 w0 = *reinterpret_cast<const float4*>(wr + 0 * 64 + o4 * 4);
        float4 w1 = *reinterpret_cast<const float4*>(wr + 1 * 64 + o4 * 4);
        float4 w2 = *reinterpret_cast<const float4*>(wr + 2 * 64 + o4 * 4);
        float4 w3 = *reinterpret_cast<const float4*>(wr + 3 * 64 + o4 * 4);
        sa [o4*4+0] += tA0*w0.x + tA1*w1.x + tA2*w2.x + tA3*w3.x;
        sa [o4*4+1] += tA0*w0.y + tA1*w1.y + tA2*w2.y + tA3*w3.y;
        sa [o4*4+2] += tA0*w0.z + tA1*w1.z + tA2*w2.z + tA3*w3.z;
        sa [o4*4+3] += tA0*w0.w + tA1*w1.w + tA2*w2.w + tA3*w3.w;
        sb_[o4*4+0] += tB0*w0.x + tB1*w1.x + tB2*w2.x + tB3*w3.x;
        sb_[o4*4+1] += tB0*w0.y + tB1*w1.y + tB2*w2.y + tB3*w3.y;
        sb_[o4*4+2] += tB0*w0.z + tB1*w1.z + tB2*w2.z + tB3*w3.z;
        sb_[o4*4+3] += tB0*w0.w + tB1*w1.w + tB2*w2.w + tB3*w3.w;
      }
    }
#pragma unroll
    for (int o = 0; o < 16; o++) agg[o] += eluf(sa[o]);
    if (hasB) {
#pragma unroll
      for (int o = 0; o < 16; o++) agg[o] += eluf(sb_[o]);
    }
  }
  float4* o4p = reinterpret_cast<float4*>(out + (size_t)dst * 64 + p * 16);
#pragma unroll
  for (int q = 0; q < 4; q++)
    o4p[q] = make_float4(agg[q*4], agg[q*4+1], agg[q*4+2], agg[q*4+3]);
  if (x2out) {
    float s = 0.f;
#pragma unroll
    for (int o = 0; o < 16; o++) s += agg[o] * agg[o];
    s += __shfl_xor(s, 1, 64);
    s += __shfl_xor(s, 2, 64);
    if (p == 0) x2out[dst] = s;
  }
}

// ---------------------------------------------------------------- graclus edge weights
// cw[gi][n] = bits( ||h1_i-h1_j|| * (invdeg_i+invdeg_j) ) for j = E[gi][n].
__global__ __launch_bounds__(256) void k_wgt(
    const float* __restrict__ h1, const float* __restrict__ x2h,
    const float* __restrict__ invdeg, const unsigned short* __restrict__ E,
    const int* __restrict__ ecnt, unsigned* __restrict__ cw)
{
  int bid = blockIdx.x;
  int swz = (bid & 7) * 16 + (bid >> 3);
  int gi = swz * 256 + threadIdx.x;
  int base = gi & ~(N_ - 1);
  float xi[64];
#pragma unroll
  for (int q = 0; q < 16; q++) {
    float4 v = reinterpret_cast<const float4*>(h1)[gi * 16 + q];
    xi[q * 4] = v.x; xi[q * 4 + 1] = v.y; xi[q * 4 + 2] = v.z; xi[q * 4 + 3] = v.w;
  }
  float x2i = x2h[gi];
  float idi = invdeg[gi];
  int cnt = ecnt[gi];
  const unsigned short* e = E + (size_t)gi * ECAP;
  unsigned* crow = cw + (size_t)gi * ECAP;
#pragma unroll 1
  for (int n = 0; n < cnt; n++) {
    int j = base + e[n];
    const float4* r = reinterpret_cast<const float4*>(h1 + (size_t)j * 64);
    float dot = 0.f;
#pragma unroll
    for (int q = 0; q < 16; q++) {
      float4 v = r[q];
      dot += xi[q * 4] * v.x + xi[q * 4 + 1] * v.y + xi[q * 4 + 2] * v.z + xi[q * 4 + 3] * v.w;
    }
    float d2 = fmaxf(x2i + x2h[j] - 2.f * dot, 0.f);
    float wgt = sqrtf(d2) * (idi + invdeg[j]);
    crow[n] = __float_as_uint(wgt);   // wgt >= 0 -> bit order == numeric order
  }
}

// ---------------------------------------------------------------- candidate sort
// One wave per node: bitonic-sort the 128 candidate slots DESCENDING by key
// (w<<32)|~j in registers (2 elems/lane, shfl_xor network), rewrite E in sorted
// order. Unused slots key=0 sort to the end. Unique keys (~j) -> deterministic,
// identical pick order to an argmax with first-index tie-break.
__global__ __launch_bounds__(256) void k_sort(
    const unsigned* __restrict__ cw, const unsigned short* __restrict__ E0,
    const int* __restrict__ ecnt, unsigned short* __restrict__ E)
{
  int node = (blockIdx.x * 256 + threadIdx.x) >> 6;
  int lane = threadIdx.x & 63;
  int cnt = ecnt[node];
  size_t rb = (size_t)node * ECAP;
  unsigned long long a = 0ull, b = 0ull;
  if (lane < cnt)
    a = ((unsigned long long)cw[rb + lane] << 32) | (unsigned)(~(unsigned)E0[rb + lane]);
  if (lane + 64 < cnt)
    b = ((unsigned long long)cw[rb + 64 + lane] << 32) | (unsigned)(~(unsigned)E0[rb + 64 + lane]);
#pragma unroll
  for (int k = 2; k <= 128; k <<= 1) {
#pragma unroll
    for (int jj = k >> 1; jj > 0; jj >>= 1) {
      if (jj == 64) {                         // partner = same lane's other element (k==128: desc)
        unsigned long long mx = a > b ? a : b;
        b = a > b ? b : a;
        a = mx;
      } else {
        unsigned long long oa = __shfl_xor(a, jj, 64);
        bool low   = (lane & jj) == 0;
        bool descA = (lane & k) == 0;
        a = ((low == descA) == (a > oa)) ? a : oa;
        unsigned long long ob = __shfl_xor(b, jj, 64);
        bool descB = (((lane + 64) & k) == 0);
        b = ((low == descB) == (b > ob)) ? b : ob;
      }
    }
  }
  E[rb + lane]      = (unsigned short)(~(unsigned)a);
  E[rb + 64 + lane] = (unsigned short)(~(unsigned)b);
}

// ---------------------------------------------------------------- graclus matching
// one wave per graph; sequential over i. Candidates sorted desc -> winner = first
// lane whose neighbor is unmatched: ballot + lowest-set-bit (no reduce chain).
// Winner lane does its own um/cluster/partner writes (no broadcast). Depth-4
// register prefetch of the u16 rows. lgkmcnt(0) publishes um within the wave.
__global__ __launch_bounds__(64) void k_graclus(
    const unsigned short* __restrict__ E, const int* __restrict__ ecnt,
    int* __restrict__ cluster, int* __restrict__ partner)
{
  __shared__ unsigned char um[N_];
  int b = blockIdx.x, lane = threadIdx.x;
  int g0 = b * N_;
  const unsigned short* Eg = E + (size_t)g0 * ECAP;
  for (int t = lane; t < N_; t += 64) { um[t] = 1; cluster[g0 + t] = t; partner[g0 + t] = -1; }
  __syncthreads();

  int jA0, jA1, cA, jB0, jB1, cB, jC0, jC1, cC, jD0, jD1, cD;
#define LOADROW(J0, J1, CN, row)                                                \
  { size_t rb_ = (size_t)(row) * ECAP;                                          \
    J0 = Eg[rb_ + lane] & (N_ - 1);                                             \
    J1 = Eg[rb_ + 64 + lane] & (N_ - 1);                                        \
    CN = ecnt[g0 + (row)]; }
  LOADROW(jA0, jA1, cA, 0)
  LOADROW(jB0, jB1, cB, 1)
  LOADROW(jC0, jC1, cC, 2)
  LOADROW(jD0, jD1, cD, 3)

  unsigned long long below = (1ull << lane) - 1ull;

  auto step = [&](int i, int j0, int j1, int cc) {
    bool ui = um[i] != 0;
    bool p0 = (lane < cc)      && ui && (um[j0] != 0);
    bool p1 = (lane + 64 < cc) && ui && (um[j1] != 0);
    unsigned long long m0 = __ballot(p0);
    unsigned long long m1 = __ballot(p1);
    bool w0 = p0 && !(m0 & below);               // I'm the lowest set bit of m0
    bool w1 = (m0 == 0ull) && p1 && !(m1 & below);
    if (w0 | w1) {
      int jw = w0 ? j0 : j1;
      um[jw] = 0;
      int r = i < jw ? i : jw;
      int o = i ^ jw ^ r;
      cluster[g0 + o] = r;
      partner[g0 + r] = o;
    }
    if (lane == 0) um[i] = 0;
    asm volatile("s_waitcnt lgkmcnt(0)" ::: "memory");  // publish um[] within the wave
  };

  for (int i = 0; i < N_; i += 4) {
    step(i, jA0, jA1, cA);
    if (i + 4 < N_) LOADROW(jA0, jA1, cA, i + 4)
    step(i + 1, jB0, jB1, cB);
    if (i + 5 < N_) LOADROW(jB0, jB1, cB, i + 5)
    step(i + 2, jC0, jC1, cC);
    if (i + 6 < N_) LOADROW(jC0, jC1, cC, i + 6)
    step(i + 3, jD0, jD1, cD);
    if (i + 7 < N_) LOADROW(jD0, jD1, cD, i + 7)
  }
#undef LOADROW
}

// ---------------------------------------------------------------- max pool
__global__ __launch_bounds__(256) void k_maxpool(
    const float* __restrict__ h1, const int* __restrict__ cluster, const int* __restrict__ partner,
    float* __restrict__ h1p, float* __restrict__ x2p, int* __restrict__ valid1,
    unsigned* __restrict__ vbits)
{
  int gi = blockIdx.x * 256 + threadIdx.x;
  int b = gi >> 10, i = gi & 1023;
  if (cluster[gi] == i) {
    int p = partner[gi];
    float s = 0.f;
#pragma unroll
    for (int q = 0; q < 16; q++) {
      float4 a = reinterpret_cast<const float4*>(h1)[gi * 16 + q];
      if (p >= 0) {
        float4 c = reinterpret_cast<const float4*>(h1)[(b * N_ + p) * 16 + q];
        a.x = fmaxf(a.x, c.x); a.y = fmaxf(a.y, c.y); a.z = fmaxf(a.z, c.z); a.w = fmaxf(a.w, c.w);
      }
      reinterpret_cast<float4*>(h1p)[gi * 16 + q] = a;
      s += a.x * a.x + a.y * a.y + a.z * a.z + a.w * a.w;
    }
    x2p[gi] = s; valid1[gi] = 1;
    atomicOr(&vbits[b * 32 + (i >> 5)], 1u << (i & 31));
  } else {
    float4 z = make_float4(0.f, 0.f, 0.f, 0.f);
#pragma unroll
    for (int q = 0; q < 16; q++) reinterpret_cast<float4*>(h1p)[gi * 16 + q] = z;
    x2p[gi] = 0.f; valid1[gi] = 0;
  }
}

// ---------------------------------------------------------------- global max + out MLP
__global__ __launch_bounds__(256) void k_final(
    const float* __restrict__ h2, const int* __restrict__ valid1,
    const float* __restrict__ o1W, const float* __restrict__ o1b,
    const float* __restrict__ o2W, const float* __restrict__ o2b,
    const float* __restrict__ o3W, const float* __restrict__ o3b,
    float* __restrict__ out)
{
  __shared__ float gm[4][64], g[64], l1[64], l2[32];
  int b = blockIdx.x, tid = threadIdx.x;
  int d = tid & 63, r = tid >> 6;
  float m = -INFF;
  for (int i = r; i < N_; i += 4) {
    if (valid1[b * N_ + i]) m = fmaxf(m, h2[(size_t)(b * N_ + i) * 64 + d]);
  }
  gm[r][d] = m;
  __syncthreads();
  if (tid < 64) g[d] = fmaxf(fmaxf(gm[0][d], gm[1][d]), fmaxf(gm[2][d], gm[3][d]));
  __syncthreads();
  if (tid < 64) {
    float a = o1b[tid];
    for (int c = 0; c < 64; c++) a += g[c] * o1W[c * 64 + tid];
    l1[tid] = elu_(a);
  }
  __syncthreads();
  if (tid < 32) {
    float a2 = o2b[tid];
    for (int c = 0; c < 64; c++) a2 += l1[c] * o2W[c * 32 + tid];
    l2[tid] = elu_(a2);
  }
  __syncthreads();
  if (tid < 2) {
    float a3 = o3b[tid];
    for (int c = 0; c < 32; c++) a3 += l2[c] * o3W[c * 2 + tid];
    out[b * 2 + tid] = a3;
  }
}

// ---------------------------------------------------------------- launch
extern "C" void kernel_launch(void* const* d_in, const int* in_sizes, int n_in,
                              void* d_out, int out_size, void* d_ws, size_t ws_size,
                              hipStream_t stream)
{
  const float* x    = (const float*)d_in[0];
  const float* nrm  = (const float*)d_in[1];
  const float* in1W = (const float*)d_in[2];  const float* in1b = (const float*)d_in[3];
  const float* in2W = (const float*)d_in[4];  const float* in2b = (const float*)d_in[5];
  const float* in3W = (const float*)d_in[6];  const float* in3b = (const float*)d_in[7];
  const float* c1aW = (const float*)d_in[8];  const float* c1ab = (const float*)d_in[9];
  const float* c1bW = (const float*)d_in[10]; const float* c1bb = (const float*)d_in[11];
  const float* c2aW = (const float*)d_in[12]; const float* c2ab = (const float*)d_in[13];
  const float* c2bW = (const float*)d_in[14]; const float* c2bb = (const float*)d_in[15];
  const float* o1W  = (const float*)d_in[16]; const float* o1b  = (const float*)d_in[17];
  const float* o2W  = (const float*)d_in[18]; const float* o2b  = (const float*)d_in[19];
  const float* o3W  = (const float*)d_in[20]; const float* o3b  = (const float*)d_in[21];

  // workspace layout. O_U is a union region with three disjoint-lifetime tenants:
  //   {pd 16MB + pix 8MB} (knn->merge)  |  {wb 12MB + vb 12MB} (uv->conv)  |  {cw 16MB} (wgt->sort)
  // h1p overlays h0; h2 overlays h1; E persists from elist1 through graclus (sorted in place
  // region), rewritten at elist2.
  constexpr size_t O_H0    = 0;                                   // h0 | h1p  (8 MB)
  constexpr size_t O_X2A   = O_H0    + (size_t)NN * 64 * 4;       // x2a | x2p
  constexpr size_t O_U     = O_X2A   + (size_t)NN * 4;            // union (24 MB)
  constexpr size_t O_K     = O_U     + (size_t)NN * NCH * 16 * 6; // K bitmask (4 MB)
  constexpr size_t O_KT    = O_K     + (size_t)NN * 32 * 4;       // KT bitmask (4 MB, contiguous after K)
  constexpr size_t O_H1    = O_KT    + (size_t)NN * 32 * 4;       // h1 | h2 (8 MB)
  constexpr size_t O_X2H   = O_H1    + (size_t)NN * 64 * 4;
  constexpr size_t O_IDG   = O_X2H   + (size_t)NN * 4;
  constexpr size_t O_ECNT  = O_IDG   + (size_t)NN * 4;
  constexpr size_t O_CLU   = O_ECNT  + (size_t)NN * 4;
  constexpr size_t O_PAR   = O_CLU   + (size_t)NN * 4;
  constexpr size_t O_VAL   = O_PAR   + (size_t)NN * 4;
  constexpr size_t O_VBITS = O_VAL   + (size_t)NN * 4;
  constexpr size_t O_E     = O_VBITS + (size_t)B_ * 32 * 4;       // edge list (8 MB)
  constexpr size_t TOTAL   = O_E     + (size_t)NN * ECAP * 2;     // ~57 MB
  if (ws_size < TOTAL) return;

  char* w = (char*)d_ws;
  float*          h0   = (float*)(w + O_H0);
  float*          x2a  = (float*)(w + O_X2A);
  float*          pdp  = (float*)(w + O_U);
  unsigned short* pip  = (unsigned short*)(w + O_U + (size_t)NN * NCH * 16 * 4);
  float*          wb   = (float*)(w + O_U);
  float*          vb   = (float*)(w + O_U + (size_t)NN * 96 * 4);
  unsigned*       cwt  = (unsigned*)(w + O_U);
  unsigned*       Kb   = (unsigned*)(w + O_K);
  unsigned*       KTb  = (unsigned*)(w + O_KT);
  float*          h1   = (float*)(w + O_H1);
  float*          x2h  = (float*)(w + O_X2H);
  float*          idg  = (float*)(w + O_IDG);
  int*            ecnt = (int*)(w + O_ECNT);
  int*            clu  = (int*)(w + O_CLU);
  int*            par  = (int*)(w + O_PAR);
  int*            val  = (int*)(w + O_VAL);
  unsigned*       vbits= (unsigned*)(w + O_VBITS);
  unsigned short* E    = (unsigned short*)(w + O_E);
  float* h1p = h0;
  float* x2p = x2a;
  float* h2  = h1;

  // ---- stage 1 (all nodes valid)
  k_input<<<NN / 256, 256, 0, stream>>>(x, nrm, in1W, in1b, in2W, in2b, in3W, in3b, h0, x2a);
  k_knn<<<B_ * 32, 256, 0, stream>>>((const float4*)h0, x2a, nullptr, nullptr, pdp, pip);
  hipMemsetAsync(KTb, 0, (size_t)NN * 32 * 4, stream);
  k_merge<<<NN / 64, 64, 0, stream>>>(pdp, pip, nullptr, Kb, KTb);
  k_elist<<<NN / 256, 256, 0, stream>>>(Kb, KTb, E, ecnt, idg);
  k_uv<<<NN / 256, 256, 0, stream>>>(h0, c1aW, c1ab, wb, vb);
  k_conv<<<NN / 64, 256, 0, stream>>>(wb, vb, E, ecnt, nullptr, c1bW, c1bb, h1, x2h);
  // ---- graclus + pool
  k_wgt<<<NN / 256, 256, 0, stream>>>(h1, x2h, idg, E, ecnt, cwt);
  k_sort<<<NN / 4, 256, 0, stream>>>(cwt, E, ecnt, E);
  k_graclus<<<B_, 64, 0, stream>>>(E, ecnt, clu, par);
  hipMemsetAsync(vbits, 0, (size_t)B_ * 32 * 4, stream);
  k_maxpool<<<NN / 256, 256, 0, stream>>>(h1, clu, par, h1p, x2p, val, vbits);
  // ---- stage 2 (valid = cluster representatives)
  k_knn<<<B_ * 32, 256, 0, stream>>>((const float4*)h1p, x2p, vbits, val, pdp, pip);
  hipMemsetAsync(Kb, 0, (size_t)NN * 32 * 4 * 2, stream);   // K and KT, contiguous
  k_merge<<<NN / 64, 64, 0, stream>>>(pdp, pip, val, Kb, KTb);
  k_elist<<<NN / 256, 256, 0, stream>>>(Kb, KTb, E, ecnt, nullptr);
  k_uv<<<NN / 256, 256, 0, stream>>>(h1p, c2aW, c2ab, wb, vb);
  k_conv<<<NN / 64, 256, 0, stream>>>(wb, vb, E, ecnt, val, c2bW, c2bb, h2, nullptr);
  k_final<<<B_, 256, 0, stream>>>(h2, val, o1W, o1b, o2W, o2b, o3W, o3b, (float*)d_out);
}

// Round 5
// 1749.738 us; speedup vs baseline: 1.1182x; 1.1182x over previous
//
#include <hip/hip_runtime.h>
#include <cmath>

// DynamicReductionNetwork forward on MI355X. All f32 (no fp32 MFMA -> vector ALU).
// input MLP -> kNN16 -> EdgeConv -> graclus -> maxpool -> kNN16 -> EdgeConv -> global max -> MLP.
// EdgeConv identity: message at dst i from source s (fwd or rev, deduped) = MLP2(elu(wb[i]+vb[s])),
// summed over the undirected neighbor set K|KT. One edge list serves conv AND graclus.
// Graclus: candidates pre-sorted desc by (w<<32|~j); matching keeps the unmatched-set as a
// 1024-bit mask in wave VGPRs (16 bits/lane) -> um tests are readlane/shfl, no LDS, no SMEM
// in the serial loop (R4 lesson: lgkmcnt(0) draining prefetch s_loads cost ~1078 cyc/step).

#define DEVI __device__ __forceinline__
constexpr int B_   = 32;
constexpr int N_   = 1024;
constexpr int NN   = B_ * N_;    // 32768 nodes
constexpr int NCH  = 8;          // knn column chunks
constexpr int CHW  = 128;        // columns per chunk
constexpr int ECAP = 128;        // edge-list cap per node (deg = 16 + in-deg)

#define INFF (__builtin_huge_valf())

DEVI float elu_(float x)  { return x > 0.f ? x : expm1f(x); }          // exact-ish (cheap kernels)
DEVI float eluf(float x)  { return x > 0.f ? x : __expf(x) - 1.f; }    // fast (conv hot loop)

// ---------------------------------------------------------------- input MLP
__global__ __launch_bounds__(256) void k_input(
    const float* __restrict__ x, const float* __restrict__ nrm,
    const float* __restrict__ w1, const float* __restrict__ b1,
    const float* __restrict__ w2, const float* __restrict__ b2,
    const float* __restrict__ w3, const float* __restrict__ b3,
    float* __restrict__ h0, float* __restrict__ x2a)
{
  __shared__ float s1[128], sb1[32], s2[2048], sb2[64], s3[4096], sb3[64];
  int tid = threadIdx.x;
  for (int t = tid; t < 128; t += 256) s1[t] = w1[t];
  if (tid < 32) sb1[tid] = b1[tid];
  for (int t = tid; t < 2048; t += 256) s2[t] = w2[t];
  if (tid < 64) sb2[tid] = b2[tid];
  for (int t = tid; t < 4096; t += 256) s3[t] = w3[t];
  if (tid < 64) sb3[tid] = b3[tid];
  __syncthreads();
  int n = blockIdx.x * 256 + tid;
  float xi[4];
#pragma unroll
  for (int d = 0; d < 4; d++) xi[d] = x[n * 4 + d] * nrm[d];
  float a1[32];
#pragma unroll
  for (int c = 0; c < 32; c++) {
    float a = sb1[c];
#pragma unroll
    for (int d = 0; d < 4; d++) a += xi[d] * s1[d * 32 + c];
    a1[c] = elu_(a);
  }
  float a2[64];
#pragma unroll
  for (int c = 0; c < 64; c++) {
    float a = sb2[c];
#pragma unroll
    for (int d = 0; d < 32; d++) a += a1[d] * s2[d * 64 + c];
    a2[c] = elu_(a);
  }
  float ss = 0.f;
#pragma unroll
  for (int c = 0; c < 64; c++) {
    float a = sb3[c];
#pragma unroll
    for (int d = 0; d < 64; d++) a += a2[d] * s3[d * 64 + c];
    a = elu_(a);
    h0[n * 64 + c] = a;
    ss += a * a;
  }
  x2a[n] = ss;
}

// ---------------------------------------------------------------- kNN partials
// per (graph, 256-row tile, 128-col chunk): per-thread sorted top-16 (d2 asc, tie -> smaller j).
__global__ __launch_bounds__(256) void k_knn(
    const float4* __restrict__ X4, const float* __restrict__ X2,
    const unsigned* __restrict__ vbits, const int* __restrict__ vrows,
    float* __restrict__ pd, unsigned short* __restrict__ pix)
{
  __shared__ float xs[CHW * 64];
  __shared__ float xs2[CHW];
  __shared__ unsigned vm[32];
  int bid = blockIdx.x;
  int swz = (bid & 7) * 128 + (bid >> 3);   // XCD swizzle (1024 blocks, %8==0 -> bijective)
  int b  = swz >> 5;
  int rt = (swz >> 3) & 3;
  int ch = swz & 7;
  int tid = threadIdx.x;
  int j0 = ch * CHW;
  for (int t = tid; t < CHW * 16; t += 256) {
    int r = t >> 4, q = t & 15;
    float4 v = X4[(b * N_ + j0 + r) * 16 + q];
    *reinterpret_cast<float4*>(&xs[r * 64 + q * 4]) = v;
  }
  for (int t = tid; t < CHW; t += 256) xs2[t] = X2[b * N_ + j0 + t];
  for (int t = tid; t < 32; t += 256) vm[t] = vbits ? vbits[b * 32 + t] : 0xFFFFFFFFu;
  __syncthreads();
  int i = rt * 256 + tid;
  int gi = b * N_ + i;
  if (vrows && !vrows[gi]) return;
  float4 xi4[16];
#pragma unroll
  for (int q = 0; q < 16; q++) xi4[q] = X4[gi * 16 + q];
  float x2i = X2[gi];
  float topd[16]; int topi[16];
#pragma unroll
  for (int q = 0; q < 16; q++) { topd[q] = INFF; topi[q] = 0xFFFF; }
  for (int jj = 0; jj < CHW; ++jj) {
    int j = j0 + jj;
    if (j == i) continue;
    if (!((vm[j >> 5] >> (j & 31)) & 1u)) continue;
    const float4* xr = reinterpret_cast<const float4*>(&xs[jj * 64]);  // b128, uniform addr -> broadcast
    float dot = 0.f;
#pragma unroll
    for (int q = 0; q < 16; q++) {
      float4 v = xr[q];
      dot += xi4[q].x * v.x + xi4[q].y * v.y + xi4[q].z * v.z + xi4[q].w * v.w;
    }
    float d2 = fmaxf(x2i + xs2[jj] - 2.f * dot, 0.f);
    if (d2 < topd[15]) {            // strict: equal keeps earlier (smaller j)
      topd[15] = d2; topi[15] = j;
#pragma unroll
      for (int p = 15; p > 0; --p) {
        if (topd[p] < topd[p - 1]) {
          float td = topd[p]; topd[p] = topd[p - 1]; topd[p - 1] = td;
          int   ti = topi[p]; topi[p] = topi[p - 1]; topi[p - 1] = ti;
        }
      }
    }
  }
  size_t base = ((size_t)gi * NCH + ch) * 16;
#pragma unroll
  for (int q = 0; q < 16; q++) { pd[base + q] = topd[q]; pix[base + q] = (unsigned short)topi[q]; }
}

// ---------------------------------------------------------------- kNN merge
// top-16 over 8 sorted partials; writes dense row bitmask K and transposed KT (atomicOr, pre-zeroed).
__global__ __launch_bounds__(64) void k_merge(
    const float* __restrict__ pd, const unsigned short* __restrict__ pix,
    const int* __restrict__ vrows,
    unsigned* __restrict__ Kb, unsigned* __restrict__ KTb)
{
  __shared__ unsigned lbm[64][33];   // 8.4 KB; per-thread row, no cross-thread use
  int tid = threadIdx.x;
  int gi = blockIdx.x * 64 + tid;
  int b = gi >> 10, i = gi & 1023;
  if (vrows && !vrows[gi]) return;
#pragma unroll
  for (int w = 0; w < 32; w++) lbm[tid][w] = 0u;
  float topd[16]; int topi[16];
#pragma unroll
  for (int q = 0; q < 16; q++) { topd[q] = INFF; topi[q] = 0; }
  for (int s = 0; s < NCH; ++s) {
    size_t base = ((size_t)gi * NCH + s) * 16;
#pragma unroll 1
    for (int q = 0; q < 16; q++) {
      float d = pd[base + q];
      if (!(d < topd[15])) break;   // partial ascending -> rest rejected too
      topd[15] = d; topi[15] = pix[base + q];
#pragma unroll
      for (int p = 15; p > 0; --p) {
        if (topd[p] < topd[p - 1]) {
          float td = topd[p]; topd[p] = topd[p - 1]; topd[p - 1] = td;
          int   ti = topi[p]; topi[p] = topi[p - 1]; topi[p - 1] = ti;
        }
      }
    }
  }
#pragma unroll
  for (int q = 0; q < 16; q++) {
    int j = topi[q];
    lbm[tid][j >> 5] |= (1u << (j & 31));
    atomicOr(&KTb[((size_t)b * N_ + j) * 32 + (i >> 5)], 1u << (i & 31));
  }
#pragma unroll
  for (int w = 0; w < 32; w++) Kb[(size_t)gi * 32 + w] = lbm[tid][w];
}

// ---------------------------------------------------------------- edge list (undirected K|KT row)
__global__ __launch_bounds__(256) void k_elist(
    const unsigned* __restrict__ Kb, const unsigned* __restrict__ KTb,
    unsigned short* __restrict__ E, int* __restrict__ ecnt, float* __restrict__ invdeg)
{
  int gi = blockIdx.x * 256 + threadIdx.x;
  unsigned short* e = E + (size_t)gi * ECAP;
  int n = 0;
  for (int w = 0; w < 32; w++) {
    unsigned m = Kb[(size_t)gi * 32 + w] | KTb[(size_t)gi * 32 + w];
    while (m) {
      int bit = __ffs(m) - 1; m &= m - 1;
      if (n < ECAP) e[n] = (unsigned short)(w * 32 + bit);
      n++;
    }
  }
  ecnt[gi] = n < ECAP ? n : ECAP;
  if (invdeg) invdeg[gi] = 1.f / (float)n;   // true degree (matches A.sum(-1))
}

// ---------------------------------------------------------------- edge MLP precompute
// wb = x@(W1[:64]-W1[64:]) + b1 ; vb = x@W1[64:]  (per-edge layer1 = wb_dst + vb_src)
__global__ __launch_bounds__(256) void k_uv(
    const float* __restrict__ X, const float* __restrict__ W1, const float* __restrict__ b1,
    float* __restrict__ wb, float* __restrict__ vb)
{
  __shared__ float wc[64 * 96], wv[64 * 96];
  int tid = threadIdx.x;
  for (int t = tid; t < 64 * 96; t += 256) {
    int d = t / 96, c = t - d * 96;
    float hv = W1[(d + 64) * 96 + c];
    wv[t] = hv;
    wc[t] = W1[d * 96 + c] - hv;
  }
  __syncthreads();
  int n = blockIdx.x * 256 + tid;
  float xi[64];
#pragma unroll
  for (int q = 0; q < 16; q++) {
    float4 v = reinterpret_cast<const float4*>(X)[n * 16 + q];
    xi[q * 4] = v.x; xi[q * 4 + 1] = v.y; xi[q * 4 + 2] = v.z; xi[q * 4 + 3] = v.w;
  }
#pragma unroll 1
  for (int c4 = 0; c4 < 24; c4++) {
    float aw0 = b1[c4 * 4 + 0], aw1 = b1[c4 * 4 + 1], aw2 = b1[c4 * 4 + 2], aw3 = b1[c4 * 4 + 3];
    float av0 = 0.f, av1 = 0.f, av2 = 0.f, av3 = 0.f;
#pragma unroll
    for (int d = 0; d < 64; d++) {
      float4 c = *reinterpret_cast<const float4*>(&wc[d * 96 + c4 * 4]);
      float4 v = *reinterpret_cast<const float4*>(&wv[d * 96 + c4 * 4]);
      float xd = xi[d];
      aw0 += xd * c.x; aw1 += xd * c.y; aw2 += xd * c.z; aw3 += xd * c.w;
      av0 += xd * v.x; av1 += xd * v.y; av2 += xd * v.z; av3 += xd * v.w;
    }
    wb[(size_t)n * 96 + c4 * 4 + 0] = aw0; wb[(size_t)n * 96 + c4 * 4 + 1] = aw1;
    wb[(size_t)n * 96 + c4 * 4 + 2] = aw2; wb[(size_t)n * 96 + c4 * 4 + 3] = aw3;
    vb[(size_t)n * 96 + c4 * 4 + 0] = av0; vb[(size_t)n * 96 + c4 * 4 + 1] = av1;
    vb[(size_t)n * 96 + c4 * 4 + 2] = av2; vb[(size_t)n * 96 + c4 * 4 + 3] = av3;
  }
}

// ---------------------------------------------------------------- EdgeConv
// 4 lanes per dst, each owns a 16-wide output slice; all lanes iterate the same
// edge list (uniform trip count); edge-pair unroll shares each w2s LDS read across 8 FMAs.
__global__ __launch_bounds__(256) void k_conv(
    const float* __restrict__ wbuf, const float* __restrict__ vbuf,
    const unsigned short* __restrict__ E, const int* __restrict__ ecnt,
    const int* __restrict__ vrows,
    const float* __restrict__ W2, const float* __restrict__ b2,
    float* __restrict__ out, float* __restrict__ x2out)
{
  __shared__ float w2s[96 * 64];
  __shared__ float b2s[64];
  __shared__ float wds[64 * 100];   // pad 100: dl*100 stride -> 2-way banks (free per m136)
  int tid = threadIdx.x;
  int bid = blockIdx.x;
  int swz = (bid & 7) * 64 + (bid >> 3);   // XCD swizzle: each XCD -> 4 contiguous graphs
  int dst0 = swz * 64;
  for (int t = tid; t < 96 * 64; t += 256) w2s[t] = W2[t];
  if (tid < 64) b2s[tid] = b2[tid];
  for (int t = tid; t < 64 * 96; t += 256) {
    int l = t / 96, c = t - l * 96;
    wds[l * 100 + c] = wbuf[(size_t)(dst0 + l) * 96 + c];
  }
  __syncthreads();
  int dl = tid >> 2, p = tid & 3;
  int dst = dst0 + dl;
  if (vrows && !vrows[dst]) return;   // quad-uniform
  int cnt = ecnt[dst];
  const unsigned short* e = E + (size_t)dst * ECAP;
  int gb = dst & ~(N_ - 1);
  float agg[16];
#pragma unroll
  for (int o = 0; o < 16; o++) agg[o] = 0.f;

#pragma unroll 1
  for (int k = 0; k < cnt; k += 2) {
    bool hasB = (k + 1 < cnt);
    int sA = gb + e[k];
    int sB = hasB ? gb + e[k + 1] : sA;
    const float4* vA = reinterpret_cast<const float4*>(vbuf + (size_t)sA * 96);
    const float4* vB = reinterpret_cast<const float4*>(vbuf + (size_t)sB * 96);
    float sa[16], sb_[16];
#pragma unroll
    for (int o = 0; o < 16; o++) { sa[o] = b2s[p * 16 + o]; sb_[o] = sa[o]; }
#pragma unroll 1
    for (int c4 = 0; c4 < 24; c4++) {
      float4 wv = *reinterpret_cast<const float4*>(&wds[dl * 100 + c4 * 4]);
      float4 a4 = vA[c4];
      float4 b4 = vB[c4];
      float tA0 = eluf(wv.x + a4.x), tA1 = eluf(wv.y + a4.y),
            tA2 = eluf(wv.z + a4.z), tA3 = eluf(wv.w + a4.w);
      float tB0 = eluf(wv.x + b4.x), tB1 = eluf(wv.y + b4.y),
            tB2 = eluf(wv.z + b4.z), tB3 = eluf(wv.w + b4.w);
      const float* wr = &w2s[(c4 * 4) * 64 + p * 16];
#pragma unroll
      for (int o4 = 0; o4 < 4; o4++) {
        float4 w0 = *reinterpret_cast<const float4*>(wr + 0 * 64 + o4 * 4);
        float4 w1 = *reinterpret_cast<const float4*>(wr + 1 * 64 + o4 * 4);
        float4 w2 = *reinterpret_cast<const float4*>(wr + 2 * 64 + o4 * 4);
        float4 w3 = *reinterpret_cast<const float4*>(wr + 3 * 64 + o4 * 4);
        sa [o4*4+0] += tA0*w0.x + tA1*w1.x + tA2*w2.x + tA3*w3.x;
        sa [o4*4+1] += tA0*w0.y + tA1*w1.y + tA2*w2.y + tA3*w3.y;
        sa [o4*4+2] += tA0*w0.z + tA1*w1.z + tA2*w2.z + tA3*w3.z;
        sa [o4*4+3] += tA0*w0.w + tA1*w1.w + tA2*w2.w + tA3*w3.w;
        sb_[o4*4+0] += tB0*w0.x + tB1*w1.x + tB2*w2.x + tB3*w3.x;
        sb_[o4*4+1] += tB0*w0.y + tB1*w1.y + tB2*w2.y + tB3*w3.y;
        sb_[o4*4+2] += tB0*w0.z + tB1*w1.z + tB2*w2.z + tB3*w3.z;
        sb_[o4*4+3] += tB0*w0.w + tB1*w1.w + tB2*w2.w + tB3*w3.w;
      }
    }
#pragma unroll
    for (int o = 0; o < 16; o++) agg[o] += eluf(sa[o]);
    if (hasB) {
#pragma unroll
      for (int o = 0; o < 16; o++) agg[o] += eluf(sb_[o]);
    }
  }
  float4* o4p = reinterpret_cast<float4*>(out + (size_t)dst * 64 + p * 16);
#pragma unroll
  for (int q = 0; q < 4; q++)
    o4p[q] = make_float4(agg[q*4], agg[q*4+1], agg[q*4+2], agg[q*4+3]);
  if (x2out) {
    float s = 0.f;
#pragma unroll
    for (int o = 0; o < 16; o++) s += agg[o] * agg[o];
    s += __shfl_xor(s, 1, 64);
    s += __shfl_xor(s, 2, 64);
    if (p == 0) x2out[dst] = s;
  }
}

// ---------------------------------------------------------------- graclus edge weights
// cw[gi][n] = bits( ||h1_i-h1_j|| * (invdeg_i+invdeg_j) ) for j = E[gi][n].
__global__ __launch_bounds__(256) void k_wgt(
    const float* __restrict__ h1, const float* __restrict__ x2h,
    const float* __restrict__ invdeg, const unsigned short* __restrict__ E,
    const int* __restrict__ ecnt, unsigned* __restrict__ cw)
{
  int bid = blockIdx.x;
  int swz = (bid & 7) * 16 + (bid >> 3);
  int gi = swz * 256 + threadIdx.x;
  int base = gi & ~(N_ - 1);
  float xi[64];
#pragma unroll
  for (int q = 0; q < 16; q++) {
    float4 v = reinterpret_cast<const float4*>(h1)[gi * 16 + q];
    xi[q * 4] = v.x; xi[q * 4 + 1] = v.y; xi[q * 4 + 2] = v.z; xi[q * 4 + 3] = v.w;
  }
  float x2i = x2h[gi];
  float idi = invdeg[gi];
  int cnt = ecnt[gi];
  const unsigned short* e = E + (size_t)gi * ECAP;
  unsigned* crow = cw + (size_t)gi * ECAP;
#pragma unroll 1
  for (int n = 0; n < cnt; n++) {
    int j = base + e[n];
    const float4* r = reinterpret_cast<const float4*>(h1 + (size_t)j * 64);
    float dot = 0.f;
#pragma unroll
    for (int q = 0; q < 16; q++) {
      float4 v = r[q];
      dot += xi[q * 4] * v.x + xi[q * 4 + 1] * v.y + xi[q * 4 + 2] * v.z + xi[q * 4 + 3] * v.w;
    }
    float d2 = fmaxf(x2i + x2h[j] - 2.f * dot, 0.f);
    float wgt = sqrtf(d2) * (idi + invdeg[j]);
    crow[n] = __float_as_uint(wgt);   // wgt >= 0 -> bit order == numeric order
  }
}

// ---------------------------------------------------------------- candidate sort
// One wave per node: bitonic-sort the 128 candidate slots DESCENDING by key
// (w<<32)|~j in registers (2 elems/lane, shfl_xor network), rewrite E in sorted
// order. Unused slots key=0 -> sort to the end, decode to 0xFFFF sentinel.
__global__ __launch_bounds__(256) void k_sort(
    const unsigned* __restrict__ cw, const unsigned short* __restrict__ E0,
    const int* __restrict__ ecnt, unsigned short* __restrict__ E)
{
  int node = (blockIdx.x * 256 + threadIdx.x) >> 6;
  int lane = threadIdx.x & 63;
  int cnt = ecnt[node];
  size_t rb = (size_t)node * ECAP;
  unsigned long long a = 0ull, b = 0ull;
  if (lane < cnt)
    a = ((unsigned long long)cw[rb + lane] << 32) | (unsigned)(~(unsigned)E0[rb + lane]);
  if (lane + 64 < cnt)
    b = ((unsigned long long)cw[rb + 64 + lane] << 32) | (unsigned)(~(unsigned)E0[rb + 64 + lane]);
#pragma unroll
  for (int k = 2; k <= 128; k <<= 1) {
#pragma unroll
    for (int jj = k >> 1; jj > 0; jj >>= 1) {
      if (jj == 64) {                         // partner = same lane's other element (k==128: desc)
        unsigned long long mx = a > b ? a : b;
        b = a > b ? b : a;
        a = mx;
      } else {
        unsigned long long oa = __shfl_xor(a, jj, 64);
        bool low   = (lane & jj) == 0;
        bool descA = (lane & k) == 0;
        a = ((low == descA) == (a > oa)) ? a : oa;
        unsigned long long ob = __shfl_xor(b, jj, 64);
        bool descB = (((lane + 64) & k) == 0);
        b = ((low == descB) == (b > ob)) ? b : ob;
      }
    }
  }
  E[rb + lane]      = (unsigned short)(~(unsigned)a);
  E[rb + 64 + lane] = (unsigned short)(~(unsigned)b);
}

// ---------------------------------------------------------------- graclus matching
// One wave per graph; sequential over i. Unmatched set = 1024-bit mask in VGPRs:
// lane L holds bits for nodes [L*16, L*16+16). Per step:
//   um[i]  (uniform)  : readlane + bit test (no LDS) -> uniform skip if matched
//   um[j]  (per-lane) : __shfl(m16, j>>4) (one bpermute round-trip, only lgkm op)
//   winner            : ballot -> s_ff1 -> readlane(j0, sw)   (no reduce chain)
//   bit clears        : pure VALU cndmask (register dep only -> next step starts at once)
// E rows sorted desc -> first valid lane == argmax (tie: min j). Sentinel 0xFFFF = empty.
__global__ __launch_bounds__(64) void k_graclus(
    const unsigned short* __restrict__ E,
    int* __restrict__ cluster, int* __restrict__ partner)
{
  int b = blockIdx.x, lane = threadIdx.x;
  int g0 = b * N_;
  const unsigned short* Eg = E + (size_t)g0 * ECAP;
  for (int t = lane; t < N_; t += 64) { cluster[g0 + t] = t; partner[g0 + t] = -1; }
  unsigned m16 = 0xFFFFu;                       // all 16 nodes of this lane unmatched
  unsigned long long below = (1ull << lane) - 1ull;

  unsigned short eA0, eA1, eB0, eB1, eC0, eC1, eD0, eD1;
#define LOADROW(E0v, E1v, row)                                                  \
  { size_t rb_ = (size_t)(row) * ECAP;                                          \
    E0v = Eg[rb_ + lane];                                                       \
    E1v = Eg[rb_ + 64 + lane]; }
  LOADROW(eA0, eA1, 0)
  LOADROW(eB0, eB1, 1)
  LOADROW(eC0, eC1, 2)
  LOADROW(eD0, eD1, 3)

  auto step = [&](int i, unsigned short e0, unsigned short e1) {
    unsigned mi = (unsigned)__builtin_amdgcn_readlane((int)m16, i >> 4);
    if ((mi >> (i & 15)) & 1u) {                // uniform branch: skip matched i
      bool v0 = e0 != 0xFFFFu, v1 = e1 != 0xFFFFu;
      int j0 = e0 & (N_ - 1), j1 = e1 & (N_ - 1);
      unsigned gm0 = (unsigned)__shfl((int)m16, j0 >> 4, 64);
      unsigned gm1 = (unsigned)__shfl((int)m16, j1 >> 4, 64);
      bool p0 = v0 && ((gm0 >> (j0 & 15)) & 1u);
      bool p1 = v1 && ((gm1 >> (j1 & 15)) & 1u);
      unsigned long long m0 = __ballot(p0);
      unsigned long long m1 = __ballot(p1);
      unsigned long long mm = m0 ? m0 : m1;
      if (mm) {                                 // uniform
        int sw = __ffsll((long long)mm) - 1;
        int jw = m0 ? __builtin_amdgcn_readlane(j0, sw)
                    : __builtin_amdgcn_readlane(j1, sw);
        unsigned clr = (lane == (jw >> 4)) ? (1u << (jw & 15)) : 0u;
        m16 &= ~clr;
        if (lane == 0) {
          int r = i < jw ? i : jw;
          int o = i ^ jw ^ r;
          cluster[g0 + o] = r;
          partner[g0 + r] = o;
        }
      }
      unsigned clri = (lane == (i >> 4)) ? (1u << (i & 15)) : 0u;
      m16 &= ~clri;
    }
  };

  for (int i = 0; i < N_; i += 4) {
    step(i, eA0, eA1);
    if (i + 4 < N_) LOADROW(eA0, eA1, i + 4)
    step(i + 1, eB0, eB1);
    if (i + 5 < N_) LOADROW(eB0, eB1, i + 5)
    step(i + 2, eC0, eC1);
    if (i + 6 < N_) LOADROW(eC0, eC1, i + 6)
    step(i + 3, eD0, eD1);
    if (i + 7 < N_) LOADROW(eD0, eD1, i + 7)
  }
#undef LOADROW
}

// ---------------------------------------------------------------- max pool
__global__ __launch_bounds__(256) void k_maxpool(
    const float* __restrict__ h1, const int* __restrict__ cluster, const int* __restrict__ partner,
    float* __restrict__ h1p, float* __restrict__ x2p, int* __restrict__ valid1,
    unsigned* __restrict__ vbits)
{
  int gi = blockIdx.x * 256 + threadIdx.x;
  int b = gi >> 10, i = gi & 1023;
  if (cluster[gi] == i) {
    int p = partner[gi];
    float s = 0.f;
#pragma unroll
    for (int q = 0; q < 16; q++) {
      float4 a = reinterpret_cast<const float4*>(h1)[gi * 16 + q];
      if (p >= 0) {
        float4 c = reinterpret_cast<const float4*>(h1)[(b * N_ + p) * 16 + q];
        a.x = fmaxf(a.x, c.x); a.y = fmaxf(a.y, c.y); a.z = fmaxf(a.z, c.z); a.w = fmaxf(a.w, c.w);
      }
      reinterpret_cast<float4*>(h1p)[gi * 16 + q] = a;
      s += a.x * a.x + a.y * a.y + a.z * a.z + a.w * a.w;
    }
    x2p[gi] = s; valid1[gi] = 1;
    atomicOr(&vbits[b * 32 + (i >> 5)], 1u << (i & 31));
  } else {
    float4 z = make_float4(0.f, 0.f, 0.f, 0.f);
#pragma unroll
    for (int q = 0; q < 16; q++) reinterpret_cast<float4*>(h1p)[gi * 16 + q] = z;
    x2p[gi] = 0.f; valid1[gi] = 0;
  }
}

// ---------------------------------------------------------------- global max + out MLP
__global__ __launch_bounds__(256) void k_final(
    const float* __restrict__ h2, const int* __restrict__ valid1,
    const float* __restrict__ o1W, const float* __restrict__ o1b,
    const float* __restrict__ o2W, const float* __restrict__ o2b,
    const float* __restrict__ o3W, const float* __restrict__ o3b,
    float* __restrict__ out)
{
  __shared__ float gm[4][64], g[64], l1[64], l2[32];
  int b = blockIdx.x, tid = threadIdx.x;
  int d = tid & 63, r = tid >> 6;
  float m = -INFF;
  for (int i = r; i < N_; i += 4) {
    if (valid1[b * N_ + i]) m = fmaxf(m, h2[(size_t)(b * N_ + i) * 64 + d]);
  }
  gm[r][d] = m;
  __syncthreads();
  if (tid < 64) g[d] = fmaxf(fmaxf(gm[0][d], gm[1][d]), fmaxf(gm[2][d], gm[3][d]));
  __syncthreads();
  if (tid < 64) {
    float a = o1b[tid];
    for (int c = 0; c < 64; c++) a += g[c] * o1W[c * 64 + tid];
    l1[tid] = elu_(a);
  }
  __syncthreads();
  if (tid < 32) {
    float a2 = o2b[tid];
    for (int c = 0; c < 64; c++) a2 += l1[c] * o2W[c * 32 + tid];
    l2[tid] = elu_(a2);
  }
  __syncthreads();
  if (tid < 2) {
    float a3 = o3b[tid];
    for (int c = 0; c < 32; c++) a3 += l2[c] * o3W[c * 2 + tid];
    out[b * 2 + tid] = a3;
  }
}

// ---------------------------------------------------------------- launch
extern "C" void kernel_launch(void* const* d_in, const int* in_sizes, int n_in,
                              void* d_out, int out_size, void* d_ws, size_t ws_size,
                              hipStream_t stream)
{
  const float* x    = (const float*)d_in[0];
  const float* nrm  = (const float*)d_in[1];
  const float* in1W = (const float*)d_in[2];  const float* in1b = (const float*)d_in[3];
  const float* in2W = (const float*)d_in[4];  const float* in2b = (const float*)d_in[5];
  const float* in3W = (const float*)d_in[6];  const float* in3b = (const float*)d_in[7];
  const float* c1aW = (const float*)d_in[8];  const float* c1ab = (const float*)d_in[9];
  const float* c1bW = (const float*)d_in[10]; const float* c1bb = (const float*)d_in[11];
  const float* c2aW = (const float*)d_in[12]; const float* c2ab = (const float*)d_in[13];
  const float* c2bW = (const float*)d_in[14]; const float* c2bb = (const float*)d_in[15];
  const float* o1W  = (const float*)d_in[16]; const float* o1b  = (const float*)d_in[17];
  const float* o2W  = (const float*)d_in[18]; const float* o2b  = (const float*)d_in[19];
  const float* o3W  = (const float*)d_in[20]; const float* o3b  = (const float*)d_in[21];

  // workspace layout. O_U is a union region with three disjoint-lifetime tenants:
  //   {pd 16MB + pix 8MB} (knn->merge)  |  {wb 12MB + vb 12MB} (uv->conv)  |  {cw 16MB} (wgt->sort)
  // h1p overlays h0; h2 overlays h1; E persists from elist1 through graclus (sorted in place
  // region), rewritten at elist2.
  constexpr size_t O_H0    = 0;                                   // h0 | h1p  (8 MB)
  constexpr size_t O_X2A   = O_H0    + (size_t)NN * 64 * 4;       // x2a | x2p
  constexpr size_t O_U     = O_X2A   + (size_t)NN * 4;            // union (24 MB)
  constexpr size_t O_K     = O_U     + (size_t)NN * NCH * 16 * 6; // K bitmask (4 MB)
  constexpr size_t O_KT    = O_K     + (size_t)NN * 32 * 4;       // KT bitmask (4 MB, contiguous after K)
  constexpr size_t O_H1    = O_KT    + (size_t)NN * 32 * 4;       // h1 | h2 (8 MB)
  constexpr size_t O_X2H   = O_H1    + (size_t)NN * 64 * 4;
  constexpr size_t O_IDG   = O_X2H   + (size_t)NN * 4;
  constexpr size_t O_ECNT  = O_IDG   + (size_t)NN * 4;
  constexpr size_t O_CLU   = O_ECNT  + (size_t)NN * 4;
  constexpr size_t O_PAR   = O_CLU   + (size_t)NN * 4;
  constexpr size_t O_VAL   = O_PAR   + (size_t)NN * 4;
  constexpr size_t O_VBITS = O_VAL   + (size_t)NN * 4;
  constexpr size_t O_E     = O_VBITS + (size_t)B_ * 32 * 4;       // edge list (8 MB)
  constexpr size_t TOTAL   = O_E     + (size_t)NN * ECAP * 2;     // ~57 MB
  if (ws_size < TOTAL) return;

  char* w = (char*)d_ws;
  float*          h0   = (float*)(w + O_H0);
  float*          x2a  = (float*)(w + O_X2A);
  float*          pdp  = (float*)(w + O_U);
  unsigned short* pip  = (unsigned short*)(w + O_U + (size_t)NN * NCH * 16 * 4);
  float*          wb   = (float*)(w + O_U);
  float*          vb   = (float*)(w + O_U + (size_t)NN * 96 * 4);
  unsigned*       cwt  = (unsigned*)(w + O_U);
  unsigned*       Kb   = (unsigned*)(w + O_K);
  unsigned*       KTb  = (unsigned*)(w + O_KT);
  float*          h1   = (float*)(w + O_H1);
  float*          x2h  = (float*)(w + O_X2H);
  float*          idg  = (float*)(w + O_IDG);
  int*            ecnt = (int*)(w + O_ECNT);
  int*            clu  = (int*)(w + O_CLU);
  int*            par  = (int*)(w + O_PAR);
  int*            val  = (int*)(w + O_VAL);
  unsigned*       vbits= (unsigned*)(w + O_VBITS);
  unsigned short* E    = (unsigned short*)(w + O_E);
  float* h1p = h0;
  float* x2p = x2a;
  float* h2  = h1;

  // ---- stage 1 (all nodes valid)
  k_input<<<NN / 256, 256, 0, stream>>>(x, nrm, in1W, in1b, in2W, in2b, in3W, in3b, h0, x2a);
  k_knn<<<B_ * 32, 256, 0, stream>>>((const float4*)h0, x2a, nullptr, nullptr, pdp, pip);
  hipMemsetAsync(KTb, 0, (size_t)NN * 32 * 4, stream);
  k_merge<<<NN / 64, 64, 0, stream>>>(pdp, pip, nullptr, Kb, KTb);
  k_elist<<<NN / 256, 256, 0, stream>>>(Kb, KTb, E, ecnt, idg);
  k_uv<<<NN / 256, 256, 0, stream>>>(h0, c1aW, c1ab, wb, vb);
  k_conv<<<NN / 64, 256, 0, stream>>>(wb, vb, E, ecnt, nullptr, c1bW, c1bb, h1, x2h);
  // ---- graclus + pool
  k_wgt<<<NN / 256, 256, 0, stream>>>(h1, x2h, idg, E, ecnt, cwt);
  k_sort<<<NN / 4, 256, 0, stream>>>(cwt, E, ecnt, E);
  k_graclus<<<B_, 64, 0, stream>>>(E, clu, par);
  hipMemsetAsync(vbits, 0, (size_t)B_ * 32 * 4, stream);
  k_maxpool<<<NN / 256, 256, 0, stream>>>(h1, clu, par, h1p, x2p, val, vbits);
  // ---- stage 2 (valid = cluster representatives)
  k_knn<<<B_ * 32, 256, 0, stream>>>((const float4*)h1p, x2p, vbits, val, pdp, pip);
  hipMemsetAsync(Kb, 0, (size_t)NN * 32 * 4 * 2, stream);   // K and KT, contiguous
  k_merge<<<NN / 64, 64, 0, stream>>>(pdp, pip, val, Kb, KTb);
  k_elist<<<NN / 256, 256, 0, stream>>>(Kb, KTb, E, ecnt, nullptr);
  k_uv<<<NN / 256, 256, 0, stream>>>(h1p, c2aW, c2ab, wb, vb);
  k_conv<<<NN / 64, 256, 0, stream>>>(wb, vb, E, ecnt, val, c2bW, c2bb, h2, nullptr);
  k_final<<<B_, 256, 0, stream>>>(h2, val, o1W, o1b, o2W, o2b, o3W, o3b, (float*)d_out);
}

// Round 6
// 1628.053 us; speedup vs baseline: 1.2017x; 1.0747x over previous
//
#include <hip/hip_runtime.h>
#include <cmath>

// DynamicReductionNetwork forward on MI355X. All f32 (no fp32 MFMA -> vector ALU).
// input MLP -> kNN16 -> EdgeConv -> graclus -> maxpool -> kNN16 -> EdgeConv -> global max -> MLP.
// EdgeConv identity: message at dst i from source s (fwd or rev, deduped) = MLP2(elu(wb[i]+vb[s])),
// summed over the undirected neighbor set K|KT. One edge list serves conv AND graclus.
// R5 lesson: k_conv was latency/imbalance-bound (occ 13.6%, VALU 46%) -> R6 adds degree-sorted
// scheduling (k_perm) so each wave's 16 dsts have uniform edge counts, + batched edge-row loads.

#define DEVI __device__ __forceinline__
constexpr int B_   = 32;
constexpr int N_   = 1024;
constexpr int NN   = B_ * N_;    // 32768 nodes
constexpr int NCH  = 8;          // knn column chunks
constexpr int CHW  = 128;        // columns per chunk
constexpr int ECAP = 128;        // edge-list cap per node (deg = 16 + in-deg)

#define INFF (__builtin_huge_valf())

DEVI float elu_(float x)  { return x > 0.f ? x : expm1f(x); }          // exact-ish (cheap kernels)
DEVI float eluf(float x)  { return x > 0.f ? x : __expf(x) - 1.f; }    // fast (conv hot loop)

// ---------------------------------------------------------------- input MLP
__global__ __launch_bounds__(256) void k_input(
    const float* __restrict__ x, const float* __restrict__ nrm,
    const float* __restrict__ w1, const float* __restrict__ b1,
    const float* __restrict__ w2, const float* __restrict__ b2,
    const float* __restrict__ w3, const float* __restrict__ b3,
    float* __restrict__ h0, float* __restrict__ x2a)
{
  __shared__ float s1[128], sb1[32], s2[2048], sb2[64], s3[4096], sb3[64];
  int tid = threadIdx.x;
  for (int t = tid; t < 128; t += 256) s1[t] = w1[t];
  if (tid < 32) sb1[tid] = b1[tid];
  for (int t = tid; t < 2048; t += 256) s2[t] = w2[t];
  if (tid < 64) sb2[tid] = b2[tid];
  for (int t = tid; t < 4096; t += 256) s3[t] = w3[t];
  if (tid < 64) sb3[tid] = b3[tid];
  __syncthreads();
  int n = blockIdx.x * 256 + tid;
  float xi[4];
#pragma unroll
  for (int d = 0; d < 4; d++) xi[d] = x[n * 4 + d] * nrm[d];
  float a1[32];
#pragma unroll
  for (int c = 0; c < 32; c++) {
    float a = sb1[c];
#pragma unroll
    for (int d = 0; d < 4; d++) a += xi[d] * s1[d * 32 + c];
    a1[c] = elu_(a);
  }
  float a2[64];
#pragma unroll
  for (int c = 0; c < 64; c++) {
    float a = sb2[c];
#pragma unroll
    for (int d = 0; d < 32; d++) a += a1[d] * s2[d * 64 + c];
    a2[c] = elu_(a);
  }
  float ss = 0.f;
#pragma unroll
  for (int c = 0; c < 64; c++) {
    float a = sb3[c];
#pragma unroll
    for (int d = 0; d < 64; d++) a += a2[d] * s3[d * 64 + c];
    a = elu_(a);
    h0[n * 64 + c] = a;
    ss += a * a;
  }
  x2a[n] = ss;
}

// ---------------------------------------------------------------- kNN partials
// per (graph, 256-row tile, 128-col chunk): per-thread sorted top-16 (d2 asc, tie -> smaller j).
__global__ __launch_bounds__(256) void k_knn(
    const float4* __restrict__ X4, const float* __restrict__ X2,
    const unsigned* __restrict__ vbits, const int* __restrict__ vrows,
    float* __restrict__ pd, unsigned short* __restrict__ pix)
{
  __shared__ float xs[CHW * 64];
  __shared__ float xs2[CHW];
  __shared__ unsigned vm[32];
  int bid = blockIdx.x;
  int swz = (bid & 7) * 128 + (bid >> 3);   // XCD swizzle (1024 blocks, %8==0 -> bijective)
  int b  = swz >> 5;
  int rt = (swz >> 3) & 3;
  int ch = swz & 7;
  int tid = threadIdx.x;
  int j0 = ch * CHW;
  for (int t = tid; t < CHW * 16; t += 256) {
    int r = t >> 4, q = t & 15;
    float4 v = X4[(b * N_ + j0 + r) * 16 + q];
    *reinterpret_cast<float4*>(&xs[r * 64 + q * 4]) = v;
  }
  for (int t = tid; t < CHW; t += 256) xs2[t] = X2[b * N_ + j0 + t];
  for (int t = tid; t < 32; t += 256) vm[t] = vbits ? vbits[b * 32 + t] : 0xFFFFFFFFu;
  __syncthreads();
  int i = rt * 256 + tid;
  int gi = b * N_ + i;
  if (vrows && !vrows[gi]) return;
  float4 xi4[16];
#pragma unroll
  for (int q = 0; q < 16; q++) xi4[q] = X4[gi * 16 + q];
  float x2i = X2[gi];
  float topd[16]; int topi[16];
#pragma unroll
  for (int q = 0; q < 16; q++) { topd[q] = INFF; topi[q] = 0xFFFF; }
  for (int jj = 0; jj < CHW; ++jj) {
    int j = j0 + jj;
    if (j == i) continue;
    if (!((vm[j >> 5] >> (j & 31)) & 1u)) continue;
    const float4* xr = reinterpret_cast<const float4*>(&xs[jj * 64]);  // b128, uniform addr -> broadcast
    float dot = 0.f;
#pragma unroll
    for (int q = 0; q < 16; q++) {
      float4 v = xr[q];
      dot += xi4[q].x * v.x + xi4[q].y * v.y + xi4[q].z * v.z + xi4[q].w * v.w;
    }
    float d2 = fmaxf(x2i + xs2[jj] - 2.f * dot, 0.f);
    if (d2 < topd[15]) {            // strict: equal keeps earlier (smaller j)
      topd[15] = d2; topi[15] = j;
#pragma unroll
      for (int p = 15; p > 0; --p) {
        if (topd[p] < topd[p - 1]) {
          float td = topd[p]; topd[p] = topd[p - 1]; topd[p - 1] = td;
          int   ti = topi[p]; topi[p] = topi[p - 1]; topi[p - 1] = ti;
        }
      }
    }
  }
  size_t base = ((size_t)gi * NCH + ch) * 16;
#pragma unroll
  for (int q = 0; q < 16; q++) { pd[base + q] = topd[q]; pix[base + q] = (unsigned short)topi[q]; }
}

// ---------------------------------------------------------------- kNN merge
// top-16 over 8 sorted partials; writes dense row bitmask K and transposed KT (atomicOr, pre-zeroed).
__global__ __launch_bounds__(64) void k_merge(
    const float* __restrict__ pd, const unsigned short* __restrict__ pix,
    const int* __restrict__ vrows,
    unsigned* __restrict__ Kb, unsigned* __restrict__ KTb)
{
  __shared__ unsigned lbm[64][33];   // 8.4 KB; per-thread row, no cross-thread use
  int tid = threadIdx.x;
  int gi = blockIdx.x * 64 + tid;
  int b = gi >> 10, i = gi & 1023;
  if (vrows && !vrows[gi]) return;
#pragma unroll
  for (int w = 0; w < 32; w++) lbm[tid][w] = 0u;
  float topd[16]; int topi[16];
#pragma unroll
  for (int q = 0; q < 16; q++) { topd[q] = INFF; topi[q] = 0; }
  for (int s = 0; s < NCH; ++s) {
    size_t base = ((size_t)gi * NCH + s) * 16;
#pragma unroll 1
    for (int q = 0; q < 16; q++) {
      float d = pd[base + q];
      if (!(d < topd[15])) break;   // partial ascending -> rest rejected too
      topd[15] = d; topi[15] = pix[base + q];
#pragma unroll
      for (int p = 15; p > 0; --p) {
        if (topd[p] < topd[p - 1]) {
          float td = topd[p]; topd[p] = topd[p - 1]; topd[p - 1] = td;
          int   ti = topi[p]; topi[p] = topi[p - 1]; topi[p - 1] = ti;
        }
      }
    }
  }
#pragma unroll
  for (int q = 0; q < 16; q++) {
    int j = topi[q];
    lbm[tid][j >> 5] |= (1u << (j & 31));
    atomicOr(&KTb[((size_t)b * N_ + j) * 32 + (i >> 5)], 1u << (i & 31));
  }
#pragma unroll
  for (int w = 0; w < 32; w++) Kb[(size_t)gi * 32 + w] = lbm[tid][w];
}

// ---------------------------------------------------------------- edge list (undirected K|KT row)
__global__ __launch_bounds__(256) void k_elist(
    const unsigned* __restrict__ Kb, const unsigned* __restrict__ KTb,
    unsigned short* __restrict__ E, int* __restrict__ ecnt, float* __restrict__ invdeg)
{
  int gi = blockIdx.x * 256 + threadIdx.x;
  unsigned short* e = E + (size_t)gi * ECAP;
  int n = 0;
  for (int w = 0; w < 32; w++) {
    unsigned m = Kb[(size_t)gi * 32 + w] | KTb[(size_t)gi * 32 + w];
    while (m) {
      int bit = __ffs(m) - 1; m &= m - 1;
      if (n < ECAP) e[n] = (unsigned short)(w * 32 + bit);
      n++;
    }
  }
  ecnt[gi] = n < ECAP ? n : ECAP;
  if (invdeg) invdeg[gi] = 1.f / (float)n;   // true degree (matches A.sum(-1))
}

// ---------------------------------------------------------------- degree permutation
// per graph: counting-sort node ids by ecnt ascending -> perm. Used by k_conv so
// each wave's 16 dsts have uniform edge counts (kills masked-lane divergence) and
// blocks get balanced heavy+light wave-group sets.
__global__ __launch_bounds__(256) void k_perm(
    const int* __restrict__ ecnt, unsigned short* __restrict__ perm)
{
  __shared__ int hist[ECAP + 1];
  __shared__ int pfx[ECAP + 1];
  int b = blockIdx.x, tid = threadIdx.x;
  int g0 = b * N_;
  for (int t = tid; t <= ECAP; t += 256) hist[t] = 0;
  __syncthreads();
  for (int t = tid; t < N_; t += 256) atomicAdd(&hist[ecnt[g0 + t]], 1);
  __syncthreads();
  if (tid == 0) {
    int s = 0;
    for (int d = 0; d <= ECAP; d++) { pfx[d] = s; s += hist[d]; }
  }
  __syncthreads();
  for (int t = tid; t < N_; t += 256) {
    int r = atomicAdd(&pfx[ecnt[g0 + t]], 1);
    perm[g0 + r] = (unsigned short)t;
  }
}

// ---------------------------------------------------------------- edge MLP precompute
// wb = x@(W1[:64]-W1[64:]) + b1 ; vb = x@W1[64:]  (per-edge layer1 = wb_dst + vb_src)
__global__ __launch_bounds__(256) void k_uv(
    const float* __restrict__ X, const float* __restrict__ W1, const float* __restrict__ b1,
    float* __restrict__ wb, float* __restrict__ vb)
{
  __shared__ float wc[64 * 96], wv[64 * 96];
  int tid = threadIdx.x;
  for (int t = tid; t < 64 * 96; t += 256) {
    int d = t / 96, c = t - d * 96;
    float hv = W1[(d + 64) * 96 + c];
    wv[t] = hv;
    wc[t] = W1[d * 96 + c] - hv;
  }
  __syncthreads();
  int n = blockIdx.x * 256 + tid;
  float xi[64];
#pragma unroll
  for (int q = 0; q < 16; q++) {
    float4 v = reinterpret_cast<const float4*>(X)[n * 16 + q];
    xi[q * 4] = v.x; xi[q * 4 + 1] = v.y; xi[q * 4 + 2] = v.z; xi[q * 4 + 3] = v.w;
  }
#pragma unroll 1
  for (int c4 = 0; c4 < 24; c4++) {
    float aw0 = b1[c4 * 4 + 0], aw1 = b1[c4 * 4 + 1], aw2 = b1[c4 * 4 + 2], aw3 = b1[c4 * 4 + 3];
    float av0 = 0.f, av1 = 0.f, av2 = 0.f, av3 = 0.f;
#pragma unroll
    for (int d = 0; d < 64; d++) {
      float4 c = *reinterpret_cast<const float4*>(&wc[d * 96 + c4 * 4]);
      float4 v = *reinterpret_cast<const float4*>(&wv[d * 96 + c4 * 4]);
      float xd = xi[d];
      aw0 += xd * c.x; aw1 += xd * c.y; aw2 += xd * c.z; aw3 += xd * c.w;
      av0 += xd * v.x; av1 += xd * v.y; av2 += xd * v.z; av3 += xd * v.w;
    }
    wb[(size_t)n * 96 + c4 * 4 + 0] = aw0; wb[(size_t)n * 96 + c4 * 4 + 1] = aw1;
    wb[(size_t)n * 96 + c4 * 4 + 2] = aw2; wb[(size_t)n * 96 + c4 * 4 + 3] = aw3;
    vb[(size_t)n * 96 + c4 * 4 + 0] = av0; vb[(size_t)n * 96 + c4 * 4 + 1] = av1;
    vb[(size_t)n * 96 + c4 * 4 + 2] = av2; vb[(size_t)n * 96 + c4 * 4 + 3] = av3;
  }
}

// ---------------------------------------------------------------- EdgeConv
// 4 lanes per dst, each owns a 16-wide output slice. Dsts assigned via degree-sorted
// perm: wave w of block kk handles sorted wave-group {kk,31-kk,32+kk,63-kk}[w]
// (uniform cnt within wave, balanced totals across blocks). cnt==0 rows (stage-2
// invalid) write zeros. Edge-pair unroll shares each w2s LDS read across 8 FMAs;
// c4-loop unrolled 4x to batch the vbuf L2 loads.
__global__ __launch_bounds__(256) void k_conv(
    const float* __restrict__ wbuf, const float* __restrict__ vbuf,
    const unsigned short* __restrict__ E, const int* __restrict__ ecnt,
    const unsigned short* __restrict__ perm,
    const float* __restrict__ W2, const float* __restrict__ b2,
    float* __restrict__ out, float* __restrict__ x2out)
{
  __shared__ float w2s[96 * 64];
  __shared__ float b2s[64];
  __shared__ float wds[64 * 100];   // pad 100: dl*100 stride -> 2-way banks (free per m136)
  __shared__ unsigned short dstl[64];
  int tid = threadIdx.x;
  int bid = blockIdx.x;
  int swz = (bid & 7) * 64 + (bid >> 3);   // XCD swizzle: each XCD -> 4 contiguous graphs
  int g  = swz >> 4, kk = swz & 15;
  int gb = g * N_;
  for (int t = tid; t < 96 * 64; t += 256) w2s[t] = W2[t];
  if (tid < 64) b2s[tid] = b2[tid];
  if (tid < 64) {
    int w = tid >> 4, r = tid & 15;
    int wg = (w == 0) ? kk : (w == 1) ? 31 - kk : (w == 2) ? 32 + kk : 63 - kk;
    dstl[tid] = perm[gb + wg * 16 + r];
  }
  __syncthreads();
  for (int t = tid; t < 64 * 96; t += 256) {
    int l = t / 96, c = t - l * 96;
    wds[l * 100 + c] = wbuf[(size_t)(gb + dstl[l]) * 96 + c];
  }
  __syncthreads();
  int dl = tid >> 2, p = tid & 3;
  int dst = gb + dstl[dl];
  int cnt = ecnt[dst];
  const unsigned short* e = E + (size_t)dst * ECAP;
  float agg[16];
#pragma unroll
  for (int o = 0; o < 16; o++) agg[o] = 0.f;

#pragma unroll 1
  for (int k = 0; k < cnt; k += 2) {
    bool hasB = (k + 1 < cnt);
    int sA = gb + e[k];
    int sB = hasB ? gb + e[k + 1] : sA;
    const float4* vA = reinterpret_cast<const float4*>(vbuf + (size_t)sA * 96);
    const float4* vB = reinterpret_cast<const float4*>(vbuf + (size_t)sB * 96);
    float sa[16], sb_[16];
#pragma unroll
    for (int o = 0; o < 16; o++) { sa[o] = b2s[p * 16 + o]; sb_[o] = sa[o]; }
#pragma unroll 4
    for (int c4 = 0; c4 < 24; c4++) {
      float4 wv = *reinterpret_cast<const float4*>(&wds[dl * 100 + c4 * 4]);
      float4 a4 = vA[c4];
      float4 b4 = vB[c4];
      float tA0 = eluf(wv.x + a4.x), tA1 = eluf(wv.y + a4.y),
            tA2 = eluf(wv.z + a4.z), tA3 = eluf(wv.w + a4.w);
      float tB0 = eluf(wv.x + b4.x), tB1 = eluf(wv.y + b4.y),
            tB2 = eluf(wv.z + b4.z), tB3 = eluf(wv.w + b4.w);
      const float* wr = &w2s[(c4 * 4) * 64 + p * 16];
#pragma unroll
      for (int o4 = 0; o4 < 4; o4++) {
        float4 w0 = *reinterpret_cast<const float4*>(wr + 0 * 64 + o4 * 4);
        float4 w1 = *reinterpret_cast<const float4*>(wr + 1 * 64 + o4 * 4);
        float4 w2 = *reinterpret_cast<const float4*>(wr + 2 * 64 + o4 * 4);
        float4 w3 = *reinterpret_cast<const float4*>(wr + 3 * 64 + o4 * 4);
        sa [o4*4+0] += tA0*w0.x + tA1*w1.x + tA2*w2.x + tA3*w3.x;
        sa [o4*4+1] += tA0*w0.y + tA1*w1.y + tA2*w2.y + tA3*w3.y;
        sa [o4*4+2] += tA0*w0.z + tA1*w1.z + tA2*w2.z + tA3*w3.z;
        sa [o4*4+3] += tA0*w0.w + tA1*w1.w + tA2*w2.w + tA3*w3.w;
        sb_[o4*4+0] += tB0*w0.x + tB1*w1.x + tB2*w2.x + tB3*w3.x;
        sb_[o4*4+1] += tB0*w0.y + tB1*w1.y + tB2*w2.y + tB3*w3.y;
        sb_[o4*4+2] += tB0*w0.z + tB1*w1.z + tB2*w2.z + tB3*w3.z;
        sb_[o4*4+3] += tB0*w0.w + tB1*w1.w + tB2*w2.w + tB3*w3.w;
      }
    }
#pragma unroll
    for (int o = 0; o < 16; o++) agg[o] += eluf(sa[o]);
    if (hasB) {
#pragma unroll
      for (int o = 0; o < 16; o++) agg[o] += eluf(sb_[o]);
    }
  }
  float4* o4p = reinterpret_cast<float4*>(out + (size_t)dst * 64 + p * 16);
#pragma unroll
  for (int q = 0; q < 4; q++)
    o4p[q] = make_float4(agg[q*4], agg[q*4+1], agg[q*4+2], agg[q*4+3]);
  if (x2out) {
    float s = 0.f;
#pragma unroll
    for (int o = 0; o < 16; o++) s += agg[o] * agg[o];
    s += __shfl_xor(s, 1, 64);
    s += __shfl_xor(s, 2, 64);
    if (p == 0) x2out[dst] = s;
  }
}

// ---------------------------------------------------------------- graclus edge weights
// cw[gi][n] = bits( ||h1_i-h1_j|| * (invdeg_i+invdeg_j) ) for j = E[gi][n].
__global__ __launch_bounds__(256) void k_wgt(
    const float* __restrict__ h1, const float* __restrict__ x2h,
    const float* __restrict__ invdeg, const unsigned short* __restrict__ E,
    const int* __restrict__ ecnt, unsigned* __restrict__ cw)
{
  int bid = blockIdx.x;
  int swz = (bid & 7) * 16 + (bid >> 3);
  int gi = swz * 256 + threadIdx.x;
  int base = gi & ~(N_ - 1);
  float xi[64];
#pragma unroll
  for (int q = 0; q < 16; q++) {
    float4 v = reinterpret_cast<const float4*>(h1)[gi * 16 + q];
    xi[q * 4] = v.x; xi[q * 4 + 1] = v.y; xi[q * 4 + 2] = v.z; xi[q * 4 + 3] = v.w;
  }
  float x2i = x2h[gi];
  float idi = invdeg[gi];
  int cnt = ecnt[gi];
  const unsigned short* e = E + (size_t)gi * ECAP;
  unsigned* crow = cw + (size_t)gi * ECAP;
#pragma unroll 1
  for (int n = 0; n < cnt; n++) {
    int j = base + e[n];
    const float4* r = reinterpret_cast<const float4*>(h1 + (size_t)j * 64);
    float dot = 0.f;
#pragma unroll
    for (int q = 0; q < 16; q++) {
      float4 v = r[q];
      dot += xi[q * 4] * v.x + xi[q * 4 + 1] * v.y + xi[q * 4 + 2] * v.z + xi[q * 4 + 3] * v.w;
    }
    float d2 = fmaxf(x2i + x2h[j] - 2.f * dot, 0.f);
    float wgt = sqrtf(d2) * (idi + invdeg[j]);
    crow[n] = __float_as_uint(wgt);   // wgt >= 0 -> bit order == numeric order
  }
}

// ---------------------------------------------------------------- candidate sort
// One wave per node: bitonic-sort the 128 candidate slots DESCENDING by key
// (w<<32)|~j in registers (2 elems/lane, shfl_xor network), rewrite E in sorted
// order. Unused slots key=0 -> sort to the end, decode to 0xFFFF sentinel.
__global__ __launch_bounds__(256) void k_sort(
    const unsigned* __restrict__ cw, const unsigned short* __restrict__ E0,
    const int* __restrict__ ecnt, unsigned short* __restrict__ E)
{
  int node = (blockIdx.x * 256 + threadIdx.x) >> 6;
  int lane = threadIdx.x & 63;
  int cnt = ecnt[node];
  size_t rb = (size_t)node * ECAP;
  unsigned long long a = 0ull, b = 0ull;
  if (lane < cnt)
    a = ((unsigned long long)cw[rb + lane] << 32) | (unsigned)(~(unsigned)E0[rb + lane]);
  if (lane + 64 < cnt)
    b = ((unsigned long long)cw[rb + 64 + lane] << 32) | (unsigned)(~(unsigned)E0[rb + 64 + lane]);
#pragma unroll
  for (int k = 2; k <= 128; k <<= 1) {
#pragma unroll
    for (int jj = k >> 1; jj > 0; jj >>= 1) {
      if (jj == 64) {                         // partner = same lane's other element (k==128: desc)
        unsigned long long mx = a > b ? a : b;
        b = a > b ? b : a;
        a = mx;
      } else {
        unsigned long long oa = __shfl_xor(a, jj, 64);
        bool low   = (lane & jj) == 0;
        bool descA = (lane & k) == 0;
        a = ((low == descA) == (a > oa)) ? a : oa;
        unsigned long long ob = __shfl_xor(b, jj, 64);
        bool descB = (((lane + 64) & k) == 0);
        b = ((low == descB) == (b > ob)) ? b : ob;
      }
    }
  }
  E[rb + lane]      = (unsigned short)(~(unsigned)a);
  E[rb + 64 + lane] = (unsigned short)(~(unsigned)b);
}

// ---------------------------------------------------------------- graclus matching
// One wave per graph; sequential over i. Unmatched set = 1024-bit mask in VGPRs:
// lane L holds bits for nodes [L*16, L*16+16). Per step:
//   um[i]  (uniform)  : readlane + bit test (no LDS) -> uniform skip if matched
//   um[j]  (per-lane) : __shfl(m16, j>>4) (one bpermute round-trip, only lgkm op)
//   winner            : ballot -> s_ff1 -> readlane(j0, sw)   (no reduce chain)
//   bit clears        : pure VALU cndmask (register dep only -> next step starts at once)
// E rows sorted desc -> first valid lane == argmax (tie: min j). Sentinel 0xFFFF = empty.
__global__ __launch_bounds__(64) void k_graclus(
    const unsigned short* __restrict__ E,
    int* __restrict__ cluster, int* __restrict__ partner)
{
  int b = blockIdx.x, lane = threadIdx.x;
  int g0 = b * N_;
  const unsigned short* Eg = E + (size_t)g0 * ECAP;
  for (int t = lane; t < N_; t += 64) { cluster[g0 + t] = t; partner[g0 + t] = -1; }
  unsigned m16 = 0xFFFFu;                       // all 16 nodes of this lane unmatched
  unsigned long long below = (1ull << lane) - 1ull;

  unsigned short eA0, eA1, eB0, eB1, eC0, eC1, eD0, eD1;
#define LOADROW(E0v, E1v, row)                                                  \
  { size_t rb_ = (size_t)(row) * ECAP;                                          \
    E0v = Eg[rb_ + lane];                                                       \
    E1v = Eg[rb_ + 64 + lane]; }
  LOADROW(eA0, eA1, 0)
  LOADROW(eB0, eB1, 1)
  LOADROW(eC0, eC1, 2)
  LOADROW(eD0, eD1, 3)

  auto step = [&](int i, unsigned short e0, unsigned short e1) {
    unsigned mi = (unsigned)__builtin_amdgcn_readlane((int)m16, i >> 4);
    if ((mi >> (i & 15)) & 1u) {                // uniform branch: skip matched i
      bool v0 = e0 != 0xFFFFu, v1 = e1 != 0xFFFFu;
      int j0 = e0 & (N_ - 1), j1 = e1 & (N_ - 1);
      unsigned gm0 = (unsigned)__shfl((int)m16, j0 >> 4, 64);
      unsigned gm1 = (unsigned)__shfl((int)m16, j1 >> 4, 64);
      bool p0 = v0 && ((gm0 >> (j0 & 15)) & 1u);
      bool p1 = v1 && ((gm1 >> (j1 & 15)) & 1u);
      unsigned long long m0 = __ballot(p0);
      unsigned long long m1 = __ballot(p1);
      unsigned long long mm = m0 ? m0 : m1;
      if (mm) {                                 // uniform
        int sw = __ffsll((long long)mm) - 1;
        int jw = m0 ? __builtin_amdgcn_readlane(j0, sw)
                    : __builtin_amdgcn_readlane(j1, sw);
        unsigned clr = (lane == (jw >> 4)) ? (1u << (jw & 15)) : 0u;
        m16 &= ~clr;
        if (lane == 0) {
          int r = i < jw ? i : jw;
          int o = i ^ jw ^ r;
          cluster[g0 + o] = r;
          partner[g0 + r] = o;
        }
      }
      unsigned clri = (lane == (i >> 4)) ? (1u << (i & 15)) : 0u;
      m16 &= ~clri;
    }
  };

  for (int i = 0; i < N_; i += 4) {
    step(i, eA0, eA1);
    if (i + 4 < N_) LOADROW(eA0, eA1, i + 4)
    step(i + 1, eB0, eB1);
    if (i + 5 < N_) LOADROW(eB0, eB1, i + 5)
    step(i + 2, eC0, eC1);
    if (i + 6 < N_) LOADROW(eC0, eC1, i + 6)
    step(i + 3, eD0, eD1);
    if (i + 7 < N_) LOADROW(eD0, eD1, i + 7)
  }
#undef LOADROW
}

// ---------------------------------------------------------------- max pool
__global__ __launch_bounds__(256) void k_maxpool(
    const float* __restrict__ h1, const int* __restrict__ cluster, const int* __restrict__ partner,
    float* __restrict__ h1p, float* __restrict__ x2p, int* __restrict__ valid1,
    unsigned* __restrict__ vbits)
{
  int gi = blockIdx.x * 256 + threadIdx.x;
  int b = gi >> 10, i = gi & 1023;
  if (cluster[gi] == i) {
    int p = partner[gi];
    float s = 0.f;
#pragma unroll
    for (int q = 0; q < 16; q++) {
      float4 a = reinterpret_cast<const float4*>(h1)[gi * 16 + q];
      if (p >= 0) {
        float4 c = reinterpret_cast<const float4*>(h1)[(b * N_ + p) * 16 + q];
        a.x = fmaxf(a.x, c.x); a.y = fmaxf(a.y, c.y); a.z = fmaxf(a.z, c.z); a.w = fmaxf(a.w, c.w);
      }
      reinterpret_cast<float4*>(h1p)[gi * 16 + q] = a;
      s += a.x * a.x + a.y * a.y + a.z * a.z + a.w * a.w;
    }
    x2p[gi] = s; valid1[gi] = 1;
    atomicOr(&vbits[b * 32 + (i >> 5)], 1u << (i & 31));
  } else {
    float4 z = make_float4(0.f, 0.f, 0.f, 0.f);
#pragma unroll
    for (int q = 0; q < 16; q++) reinterpret_cast<float4*>(h1p)[gi * 16 + q] = z;
    x2p[gi] = 0.f; valid1[gi] = 0;
  }
}

// ---------------------------------------------------------------- global max + out MLP
__global__ __launch_bounds__(256) void k_final(
    const float* __restrict__ h2, const int* __restrict__ valid1,
    const float* __restrict__ o1W, const float* __restrict__ o1b,
    const float* __restrict__ o2W, const float* __restrict__ o2b,
    const float* __restrict__ o3W, const float* __restrict__ o3b,
    float* __restrict__ out)
{
  __shared__ float gm[4][64], g[64], l1[64], l2[32];
  int b = blockIdx.x, tid = threadIdx.x;
  int d = tid & 63, r = tid >> 6;
  float m = -INFF;
  for (int i = r; i < N_; i += 4) {
    if (valid1[b * N_ + i]) m = fmaxf(m, h2[(size_t)(b * N_ + i) * 64 + d]);
  }
  gm[r][d] = m;
  __syncthreads();
  if (tid < 64) g[d] = fmaxf(fmaxf(gm[0][d], gm[1][d]), fmaxf(gm[2][d], gm[3][d]));
  __syncthreads();
  if (tid < 64) {
    float a = o1b[tid];
    for (int c = 0; c < 64; c++) a += g[c] * o1W[c * 64 + tid];
    l1[tid] = elu_(a);
  }
  __syncthreads();
  if (tid < 32) {
    float a2 = o2b[tid];
    for (int c = 0; c < 64; c++) a2 += l1[c] * o2W[c * 32 + tid];
    l2[tid] = elu_(a2);
  }
  __syncthreads();
  if (tid < 2) {
    float a3 = o3b[tid];
    for (int c = 0; c < 32; c++) a3 += l2[c] * o3W[c * 2 + tid];
    out[b * 2 + tid] = a3;
  }
}

// ---------------------------------------------------------------- launch
extern "C" void kernel_launch(void* const* d_in, const int* in_sizes, int n_in,
                              void* d_out, int out_size, void* d_ws, size_t ws_size,
                              hipStream_t stream)
{
  const float* x    = (const float*)d_in[0];
  const float* nrm  = (const float*)d_in[1];
  const float* in1W = (const float*)d_in[2];  const float* in1b = (const float*)d_in[3];
  const float* in2W = (const float*)d_in[4];  const float* in2b = (const float*)d_in[5];
  const float* in3W = (const float*)d_in[6];  const float* in3b = (const float*)d_in[7];
  const float* c1aW = (const float*)d_in[8];  const float* c1ab = (const float*)d_in[9];
  const float* c1bW = (const float*)d_in[10]; const float* c1bb = (const float*)d_in[11];
  const float* c2aW = (const float*)d_in[12]; const float* c2ab = (const float*)d_in[13];
  const float* c2bW = (const float*)d_in[14]; const float* c2bb = (const float*)d_in[15];
  const float* o1W  = (const float*)d_in[16]; const float* o1b  = (const float*)d_in[17];
  const float* o2W  = (const float*)d_in[18]; const float* o2b  = (const float*)d_in[19];
  const float* o3W  = (const float*)d_in[20]; const float* o3b  = (const float*)d_in[21];

  // workspace layout. O_U is a union region with three disjoint-lifetime tenants:
  //   {pd 16MB + pix 8MB} (knn->merge)  |  {wb 12MB + vb 12MB} (uv->conv)  |  {cw 16MB} (wgt->sort)
  // h1p overlays h0; h2 overlays h1; E persists from elist1 through graclus (sorted in place
  // region), rewritten at elist2. perm rebuilt per stage after its k_elist.
  constexpr size_t O_H0    = 0;                                   // h0 | h1p  (8 MB)
  constexpr size_t O_X2A   = O_H0    + (size_t)NN * 64 * 4;       // x2a | x2p
  constexpr size_t O_U     = O_X2A   + (size_t)NN * 4;            // union (24 MB)
  constexpr size_t O_K     = O_U     + (size_t)NN * NCH * 16 * 6; // K bitmask (4 MB)
  constexpr size_t O_KT    = O_K     + (size_t)NN * 32 * 4;       // KT bitmask (4 MB, contiguous after K)
  constexpr size_t O_H1    = O_KT    + (size_t)NN * 32 * 4;       // h1 | h2 (8 MB)
  constexpr size_t O_X2H   = O_H1    + (size_t)NN * 64 * 4;
  constexpr size_t O_IDG   = O_X2H   + (size_t)NN * 4;
  constexpr size_t O_ECNT  = O_IDG   + (size_t)NN * 4;
  constexpr size_t O_CLU   = O_ECNT  + (size_t)NN * 4;
  constexpr size_t O_PAR   = O_CLU   + (size_t)NN * 4;
  constexpr size_t O_VAL   = O_PAR   + (size_t)NN * 4;
  constexpr size_t O_VBITS = O_VAL   + (size_t)NN * 4;
  constexpr size_t O_E     = O_VBITS + (size_t)B_ * 32 * 4;       // edge list (8 MB)
  constexpr size_t O_PERM  = O_E     + (size_t)NN * ECAP * 2;     // degree perm (64 KB)
  constexpr size_t TOTAL   = O_PERM  + (size_t)NN * 2;            // ~57 MB
  if (ws_size < TOTAL) return;

  char* w = (char*)d_ws;
  float*          h0   = (float*)(w + O_H0);
  float*          x2a  = (float*)(w + O_X2A);
  float*          pdp  = (float*)(w + O_U);
  unsigned short* pip  = (unsigned short*)(w + O_U + (size_t)NN * NCH * 16 * 4);
  float*          wb   = (float*)(w + O_U);
  float*          vb   = (float*)(w + O_U + (size_t)NN * 96 * 4);
  unsigned*       cwt  = (unsigned*)(w + O_U);
  unsigned*       Kb   = (unsigned*)(w + O_K);
  unsigned*       KTb  = (unsigned*)(w + O_KT);
  float*          h1   = (float*)(w + O_H1);
  float*          x2h  = (float*)(w + O_X2H);
  float*          idg  = (float*)(w + O_IDG);
  int*            ecnt = (int*)(w + O_ECNT);
  int*            clu  = (int*)(w + O_CLU);
  int*            par  = (int*)(w + O_PAR);
  int*            val  = (int*)(w + O_VAL);
  unsigned*       vbits= (unsigned*)(w + O_VBITS);
  unsigned short* E    = (unsigned short*)(w + O_E);
  unsigned short* perm = (unsigned short*)(w + O_PERM);
  float* h1p = h0;
  float* x2p = x2a;
  float* h2  = h1;

  // ---- stage 1 (all nodes valid)
  k_input<<<NN / 256, 256, 0, stream>>>(x, nrm, in1W, in1b, in2W, in2b, in3W, in3b, h0, x2a);
  k_knn<<<B_ * 32, 256, 0, stream>>>((const float4*)h0, x2a, nullptr, nullptr, pdp, pip);
  hipMemsetAsync(KTb, 0, (size_t)NN * 32 * 4, stream);
  k_merge<<<NN / 64, 64, 0, stream>>>(pdp, pip, nullptr, Kb, KTb);
  k_elist<<<NN / 256, 256, 0, stream>>>(Kb, KTb, E, ecnt, idg);
  k_perm<<<B_, 256, 0, stream>>>(ecnt, perm);
  k_uv<<<NN / 256, 256, 0, stream>>>(h0, c1aW, c1ab, wb, vb);
  k_conv<<<NN / 64, 256, 0, stream>>>(wb, vb, E, ecnt, perm, c1bW, c1bb, h1, x2h);
  // ---- graclus + pool
  k_wgt<<<NN / 256, 256, 0, stream>>>(h1, x2h, idg, E, ecnt, cwt);
  k_sort<<<NN / 4, 256, 0, stream>>>(cwt, E, ecnt, E);
  k_graclus<<<B_, 64, 0, stream>>>(E, clu, par);
  hipMemsetAsync(vbits, 0, (size_t)B_ * 32 * 4, stream);
  k_maxpool<<<NN / 256, 256, 0, stream>>>(h1, clu, par, h1p, x2p, val, vbits);
  // ---- stage 2 (valid = cluster representatives; invalid rows have ecnt==0)
  k_knn<<<B_ * 32, 256, 0, stream>>>((const float4*)h1p, x2p, vbits, val, pdp, pip);
  hipMemsetAsync(Kb, 0, (size_t)NN * 32 * 4 * 2, stream);   // K and KT, contiguous
  k_merge<<<NN / 64, 64, 0, stream>>>(pdp, pip, val, Kb, KTb);
  k_elist<<<NN / 256, 256, 0, stream>>>(Kb, KTb, E, ecnt, nullptr);
  k_perm<<<B_, 256, 0, stream>>>(ecnt, perm);
  k_uv<<<NN / 256, 256, 0, stream>>>(h1p, c2aW, c2ab, wb, vb);
  k_conv<<<NN / 64, 256, 0, stream>>>(wb, vb, E, ecnt, perm, c2bW, c2bb, h2, nullptr);
  k_final<<<B_, 256, 0, stream>>>(h2, val, o1W, o1b, o2W, o2b, o3W, o3b, (float*)d_out);
}

// Round 8
// 1623.858 us; speedup vs baseline: 1.2048x; 1.0026x over previous
//
#include <hip/hip_runtime.h>
#include <cmath>

// DynamicReductionNetwork forward on MI355X. All f32 (no fp32 MFMA -> vector ALU).
// input MLP -> kNN16 -> EdgeConv -> graclus -> maxpool -> kNN16 -> EdgeConv -> global max -> MLP.
// EdgeConv identity: message at dst i from source s (fwd or rev, deduped) = MLP2(elu(wb[i]+vb[s])),
// summed over the undirected neighbor set K|KT. One edge list serves conv AND graclus.
// R6 lesson: global stores inside graclus' serial loop force vmcnt(0) drains (595 cy/step).
// R7: results buffered in LDS, flushed post-loop -> only counted prefetch loads in vmcnt.

#define DEVI __device__ __forceinline__
constexpr int B_   = 32;
constexpr int N_   = 1024;
constexpr int NN   = B_ * N_;    // 32768 nodes
constexpr int NCH  = 8;          // knn column chunks
constexpr int CHW  = 128;        // columns per chunk
constexpr int ECAP = 128;        // edge-list cap per node (deg = 16 + in-deg)

#define INFF (__builtin_huge_valf())

DEVI float elu_(float x)  { return x > 0.f ? x : expm1f(x); }          // exact-ish (cheap kernels)
DEVI float eluf(float x)  { return x > 0.f ? x : __expf(x) - 1.f; }    // fast (conv hot loop)

// ---------------------------------------------------------------- input MLP
__global__ __launch_bounds__(256) void k_input(
    const float* __restrict__ x, const float* __restrict__ nrm,
    const float* __restrict__ w1, const float* __restrict__ b1,
    const float* __restrict__ w2, const float* __restrict__ b2,
    const float* __restrict__ w3, const float* __restrict__ b3,
    float* __restrict__ h0, float* __restrict__ x2a)
{
  __shared__ float s1[128], sb1[32], s2[2048], sb2[64], s3[4096], sb3[64];
  int tid = threadIdx.x;
  for (int t = tid; t < 128; t += 256) s1[t] = w1[t];
  if (tid < 32) sb1[tid] = b1[tid];
  for (int t = tid; t < 2048; t += 256) s2[t] = w2[t];
  if (tid < 64) sb2[tid] = b2[tid];
  for (int t = tid; t < 4096; t += 256) s3[t] = w3[t];
  if (tid < 64) sb3[tid] = b3[tid];
  __syncthreads();
  int n = blockIdx.x * 256 + tid;
  float xi[4];
#pragma unroll
  for (int d = 0; d < 4; d++) xi[d] = x[n * 4 + d] * nrm[d];
  float a1[32];
#pragma unroll
  for (int c = 0; c < 32; c++) {
    float a = sb1[c];
#pragma unroll
    for (int d = 0; d < 4; d++) a += xi[d] * s1[d * 32 + c];
    a1[c] = elu_(a);
  }
  float a2[64];
#pragma unroll
  for (int c = 0; c < 64; c++) {
    float a = sb2[c];
#pragma unroll
    for (int d = 0; d < 32; d++) a += a1[d] * s2[d * 64 + c];
    a2[c] = elu_(a);
  }
  float ss = 0.f;
#pragma unroll
  for (int c = 0; c < 64; c++) {
    float a = sb3[c];
#pragma unroll
    for (int d = 0; d < 64; d++) a += a2[d] * s3[d * 64 + c];
    a = elu_(a);
    h0[n * 64 + c] = a;
    ss += a * a;
  }
  x2a[n] = ss;
}

// ---------------------------------------------------------------- kNN partials
// per (graph, 256-row tile, 128-col chunk): per-thread sorted top-16 (d2 asc, tie -> smaller j).
__global__ __launch_bounds__(256) void k_knn(
    const float4* __restrict__ X4, const float* __restrict__ X2,
    const unsigned* __restrict__ vbits, const int* __restrict__ vrows,
    float* __restrict__ pd, unsigned short* __restrict__ pix)
{
  __shared__ float xs[CHW * 64];
  __shared__ float xs2[CHW];
  __shared__ unsigned vm[32];
  int bid = blockIdx.x;
  int swz = (bid & 7) * 128 + (bid >> 3);   // XCD swizzle (1024 blocks, %8==0 -> bijective)
  int b  = swz >> 5;
  int rt = (swz >> 3) & 3;
  int ch = swz & 7;
  int tid = threadIdx.x;
  int j0 = ch * CHW;
  for (int t = tid; t < CHW * 16; t += 256) {
    int r = t >> 4, q = t & 15;
    float4 v = X4[(b * N_ + j0 + r) * 16 + q];
    *reinterpret_cast<float4*>(&xs[r * 64 + q * 4]) = v;
  }
  for (int t = tid; t < CHW; t += 256) xs2[t] = X2[b * N_ + j0 + t];
  for (int t = tid; t < 32; t += 256) vm[t] = vbits ? vbits[b * 32 + t] : 0xFFFFFFFFu;
  __syncthreads();
  int i = rt * 256 + tid;
  int gi = b * N_ + i;
  if (vrows && !vrows[gi]) return;
  float4 xi4[16];
#pragma unroll
  for (int q = 0; q < 16; q++) xi4[q] = X4[gi * 16 + q];
  float x2i = X2[gi];
  float topd[16]; int topi[16];
#pragma unroll
  for (int q = 0; q < 16; q++) { topd[q] = INFF; topi[q] = 0xFFFF; }
  for (int jj = 0; jj < CHW; ++jj) {
    int j = j0 + jj;
    if (j == i) continue;
    if (!((vm[j >> 5] >> (j & 31)) & 1u)) continue;
    const float4* xr = reinterpret_cast<const float4*>(&xs[jj * 64]);  // b128, uniform addr -> broadcast
    float dot = 0.f;
#pragma unroll
    for (int q = 0; q < 16; q++) {
      float4 v = xr[q];
      dot += xi4[q].x * v.x + xi4[q].y * v.y + xi4[q].z * v.z + xi4[q].w * v.w;
    }
    float d2 = fmaxf(x2i + xs2[jj] - 2.f * dot, 0.f);
    if (d2 < topd[15]) {            // strict: equal keeps earlier (smaller j)
      topd[15] = d2; topi[15] = j;
#pragma unroll
      for (int p = 15; p > 0; --p) {
        if (topd[p] < topd[p - 1]) {
          float td = topd[p]; topd[p] = topd[p - 1]; topd[p - 1] = td;
          int   ti = topi[p]; topi[p] = topi[p - 1]; topi[p - 1] = ti;
        }
      }
    }
  }
  size_t base = ((size_t)gi * NCH + ch) * 16;
#pragma unroll
  for (int q = 0; q < 16; q++) { pd[base + q] = topd[q]; pix[base + q] = (unsigned short)topi[q]; }
}

// ---------------------------------------------------------------- kNN merge
// top-16 over 8 sorted partials; writes dense row bitmask K and transposed KT (atomicOr, pre-zeroed).
__global__ __launch_bounds__(64) void k_merge(
    const float* __restrict__ pd, const unsigned short* __restrict__ pix,
    const int* __restrict__ vrows,
    unsigned* __restrict__ Kb, unsigned* __restrict__ KTb)
{
  __shared__ unsigned lbm[64][33];   // 8.4 KB; per-thread row, no cross-thread use
  int tid = threadIdx.x;
  int gi = blockIdx.x * 64 + tid;
  int b = gi >> 10, i = gi & 1023;
  if (vrows && !vrows[gi]) return;
#pragma unroll
  for (int w = 0; w < 32; w++) lbm[tid][w] = 0u;
  float topd[16]; int topi[16];
#pragma unroll
  for (int q = 0; q < 16; q++) { topd[q] = INFF; topi[q] = 0; }
  for (int s = 0; s < NCH; ++s) {
    size_t base = ((size_t)gi * NCH + s) * 16;
#pragma unroll 1
    for (int q = 0; q < 16; q++) {
      float d = pd[base + q];
      if (!(d < topd[15])) break;   // partial ascending -> rest rejected too
      topd[15] = d; topi[15] = pix[base + q];
#pragma unroll
      for (int p = 15; p > 0; --p) {
        if (topd[p] < topd[p - 1]) {
          float td = topd[p]; topd[p] = topd[p - 1]; topd[p - 1] = td;
          int   ti = topi[p]; topi[p] = topi[p - 1]; topi[p - 1] = ti;
        }
      }
    }
  }
#pragma unroll
  for (int q = 0; q < 16; q++) {
    int j = topi[q];
    lbm[tid][j >> 5] |= (1u << (j & 31));
    atomicOr(&KTb[((size_t)b * N_ + j) * 32 + (i >> 5)], 1u << (i & 31));
  }
#pragma unroll
  for (int w = 0; w < 32; w++) Kb[(size_t)gi * 32 + w] = lbm[tid][w];
}

// ---------------------------------------------------------------- edge list (undirected K|KT row)
__global__ __launch_bounds__(256) void k_elist(
    const unsigned* __restrict__ Kb, const unsigned* __restrict__ KTb,
    unsigned short* __restrict__ E, int* __restrict__ ecnt, float* __restrict__ invdeg)
{
  int gi = blockIdx.x * 256 + threadIdx.x;
  unsigned short* e = E + (size_t)gi * ECAP;
  int n = 0;
  for (int w = 0; w < 32; w++) {
    unsigned m = Kb[(size_t)gi * 32 + w] | KTb[(size_t)gi * 32 + w];
    while (m) {
      int bit = __ffs(m) - 1; m &= m - 1;
      if (n < ECAP) e[n] = (unsigned short)(w * 32 + bit);
      n++;
    }
  }
  ecnt[gi] = n < ECAP ? n : ECAP;
  if (invdeg) invdeg[gi] = 1.f / (float)n;   // true degree (matches A.sum(-1))
}

// ---------------------------------------------------------------- degree permutation
// per graph: counting-sort node ids by ecnt ascending -> perm. Used by k_conv so
// each wave's 16 dsts have uniform edge counts (kills masked-lane divergence) and
// blocks get balanced heavy+light wave-group sets.
__global__ __launch_bounds__(256) void k_perm(
    const int* __restrict__ ecnt, unsigned short* __restrict__ perm)
{
  __shared__ int hist[ECAP + 1];
  __shared__ int pfx[ECAP + 1];
  int b = blockIdx.x, tid = threadIdx.x;
  int g0 = b * N_;
  for (int t = tid; t <= ECAP; t += 256) hist[t] = 0;
  __syncthreads();
  for (int t = tid; t < N_; t += 256) atomicAdd(&hist[ecnt[g0 + t]], 1);
  __syncthreads();
  if (tid == 0) {
    int s = 0;
    for (int d = 0; d <= ECAP; d++) { pfx[d] = s; s += hist[d]; }
  }
  __syncthreads();
  for (int t = tid; t < N_; t += 256) {
    int r = atomicAdd(&pfx[ecnt[g0 + t]], 1);
    perm[g0 + r] = (unsigned short)t;
  }
}

// ---------------------------------------------------------------- edge MLP precompute
// wb = x@(W1[:64]-W1[64:]) + b1 ; vb = x@W1[64:]  (per-edge layer1 = wb_dst + vb_src)
__global__ __launch_bounds__(256) void k_uv(
    const float* __restrict__ X, const float* __restrict__ W1, const float* __restrict__ b1,
    float* __restrict__ wb, float* __restrict__ vb)
{
  __shared__ float wc[64 * 96], wv[64 * 96];
  int tid = threadIdx.x;
  for (int t = tid; t < 64 * 96; t += 256) {
    int d = t / 96, c = t - d * 96;
    float hv = W1[(d + 64) * 96 + c];
    wv[t] = hv;
    wc[t] = W1[d * 96 + c] - hv;
  }
  __syncthreads();
  int n = blockIdx.x * 256 + tid;
  float xi[64];
#pragma unroll
  for (int q = 0; q < 16; q++) {
    float4 v = reinterpret_cast<const float4*>(X)[n * 16 + q];
    xi[q * 4] = v.x; xi[q * 4 + 1] = v.y; xi[q * 4 + 2] = v.z; xi[q * 4 + 3] = v.w;
  }
#pragma unroll 1
  for (int c4 = 0; c4 < 24; c4++) {
    float aw0 = b1[c4 * 4 + 0], aw1 = b1[c4 * 4 + 1], aw2 = b1[c4 * 4 + 2], aw3 = b1[c4 * 4 + 3];
    float av0 = 0.f, av1 = 0.f, av2 = 0.f, av3 = 0.f;
#pragma unroll
    for (int d = 0; d < 64; d++) {
      float4 c = *reinterpret_cast<const float4*>(&wc[d * 96 + c4 * 4]);
      float4 v = *reinterpret_cast<const float4*>(&wv[d * 96 + c4 * 4]);
      float xd = xi[d];
      aw0 += xd * c.x; aw1 += xd * c.y; aw2 += xd * c.z; aw3 += xd * c.w;
      av0 += xd * v.x; av1 += xd * v.y; av2 += xd * v.z; av3 += xd * v.w;
    }
    wb[(size_t)n * 96 + c4 * 4 + 0] = aw0; wb[(size_t)n * 96 + c4 * 4 + 1] = aw1;
    wb[(size_t)n * 96 + c4 * 4 + 2] = aw2; wb[(size_t)n * 96 + c4 * 4 + 3] = aw3;
    vb[(size_t)n * 96 + c4 * 4 + 0] = av0; vb[(size_t)n * 96 + c4 * 4 + 1] = av1;
    vb[(size_t)n * 96 + c4 * 4 + 2] = av2; vb[(size_t)n * 96 + c4 * 4 + 3] = av3;
  }
}

// ---------------------------------------------------------------- EdgeConv
// 4 lanes per dst, each owns a 16-wide output slice. Dsts assigned via degree-sorted
// perm: wave w of block kk handles sorted wave-group {kk,31-kk,32+kk,63-kk}[w]
// (uniform cnt within wave, balanced totals across blocks). cnt==0 rows (stage-2
// invalid) write zeros. Edge-pair unroll shares each w2s LDS read across 8 FMAs;
// c4-loop unrolled 4x to batch the vbuf L2 loads.
__global__ __launch_bounds__(256) void k_conv(
    const float* __restrict__ wbuf, const float* __restrict__ vbuf,
    const unsigned short* __restrict__ E, const int* __restrict__ ecnt,
    const unsigned short* __restrict__ perm,
    const float* __restrict__ W2, const float* __restrict__ b2,
    float* __restrict__ out, float* __restrict__ x2out)
{
  __shared__ float w2s[96 * 64];
  __shared__ float b2s[64];
  __shared__ float wds[64 * 100];   // pad 100: dl*100 stride -> 2-way banks (free per m136)
  __shared__ unsigned short dstl[64];
  int tid = threadIdx.x;
  int bid = blockIdx.x;
  int swz = (bid & 7) * 64 + (bid >> 3);   // XCD swizzle: each XCD -> 4 contiguous graphs
  int g  = swz >> 4, kk = swz & 15;
  int gb = g * N_;
  for (int t = tid; t < 96 * 64; t += 256) w2s[t] = W2[t];
  if (tid < 64) b2s[tid] = b2[tid];
  if (tid < 64) {
    int w = tid >> 4, r = tid & 15;
    int wg = (w == 0) ? kk : (w == 1) ? 31 - kk : (w == 2) ? 32 + kk : 63 - kk;
    dstl[tid] = perm[gb + wg * 16 + r];
  }
  __syncthreads();
  for (int t = tid; t < 64 * 96; t += 256) {
    int l = t / 96, c = t - l * 96;
    wds[l * 100 + c] = wbuf[(size_t)(gb + dstl[l]) * 96 + c];
  }
  __syncthreads();
  int dl = tid >> 2, p = tid & 3;
  int dst = gb + dstl[dl];
  int cnt = ecnt[dst];
  const unsigned short* e = E + (size_t)dst * ECAP;
  float agg[16];
#pragma unroll
  for (int o = 0; o < 16; o++) agg[o] = 0.f;

#pragma unroll 1
  for (int k = 0; k < cnt; k += 2) {
    bool hasB = (k + 1 < cnt);
    int sA = gb + e[k];
    int sB = hasB ? gb + e[k + 1] : sA;
    const float4* vA = reinterpret_cast<const float4*>(vbuf + (size_t)sA * 96);
    const float4* vB = reinterpret_cast<const float4*>(vbuf + (size_t)sB * 96);
    float sa[16], sb_[16];
#pragma unroll
    for (int o = 0; o < 16; o++) { sa[o] = b2s[p * 16 + o]; sb_[o] = sa[o]; }
#pragma unroll 4
    for (int c4 = 0; c4 < 24; c4++) {
      float4 wv = *reinterpret_cast<const float4*>(&wds[dl * 100 + c4 * 4]);
      float4 a4 = vA[c4];
      float4 b4 = vB[c4];
      float tA0 = eluf(wv.x + a4.x), tA1 = eluf(wv.y + a4.y),
            tA2 = eluf(wv.z + a4.z), tA3 = eluf(wv.w + a4.w);
      float tB0 = eluf(wv.x + b4.x), tB1 = eluf(wv.y + b4.y),
            tB2 = eluf(wv.z + b4.z), tB3 = eluf(wv.w + b4.w);
      const float* wr = &w2s[(c4 * 4) * 64 + p * 16];
#pragma unroll
      for (int o4 = 0; o4 < 4; o4++) {
        float4 w0 = *reinterpret_cast<const float4*>(wr + 0 * 64 + o4 * 4);
        float4 w1 = *reinterpret_cast<const float4*>(wr + 1 * 64 + o4 * 4);
        float4 w2 = *reinterpret_cast<const float4*>(wr + 2 * 64 + o4 * 4);
        float4 w3 = *reinterpret_cast<const float4*>(wr + 3 * 64 + o4 * 4);
        sa [o4*4+0] += tA0*w0.x + tA1*w1.x + tA2*w2.x + tA3*w3.x;
        sa [o4*4+1] += tA0*w0.y + tA1*w1.y + tA2*w2.y + tA3*w3.y;
        sa [o4*4+2] += tA0*w0.z + tA1*w1.z + tA2*w2.z + tA3*w3.z;
        sa [o4*4+3] += tA0*w0.w + tA1*w1.w + tA2*w2.w + tA3*w3.w;
        sb_[o4*4+0] += tB0*w0.x + tB1*w1.x + tB2*w2.x + tB3*w3.x;
        sb_[o4*4+1] += tB0*w0.y + tB1*w1.y + tB2*w2.y + tB3*w3.y;
        sb_[o4*4+2] += tB0*w0.z + tB1*w1.z + tB2*w2.z + tB3*w3.z;
        sb_[o4*4+3] += tB0*w0.w + tB1*w1.w + tB2*w2.w + tB3*w3.w;
      }
    }
#pragma unroll
    for (int o = 0; o < 16; o++) agg[o] += eluf(sa[o]);
    if (hasB) {
#pragma unroll
      for (int o = 0; o < 16; o++) agg[o] += eluf(sb_[o]);
    }
  }
  float4* o4p = reinterpret_cast<float4*>(out + (size_t)dst * 64 + p * 16);
#pragma unroll
  for (int q = 0; q < 4; q++)
    o4p[q] = make_float4(agg[q*4], agg[q*4+1], agg[q*4+2], agg[q*4+3]);
  if (x2out) {
    float s = 0.f;
#pragma unroll
    for (int o = 0; o < 16; o++) s += agg[o] * agg[o];
    s += __shfl_xor(s, 1, 64);
    s += __shfl_xor(s, 2, 64);
    if (p == 0) x2out[dst] = s;
  }
}

// ---------------------------------------------------------------- graclus edge weights
// cw[gi][n] = bits( ||h1_i-h1_j|| * (invdeg_i+invdeg_j) ) for j = E[gi][n].
__global__ __launch_bounds__(256) void k_wgt(
    const float* __restrict__ h1, const float* __restrict__ x2h,
    const float* __restrict__ invdeg, const unsigned short* __restrict__ E,
    const int* __restrict__ ecnt, unsigned* __restrict__ cw)
{
  int bid = blockIdx.x;
  int swz = (bid & 7) * 16 + (bid >> 3);
  int gi = swz * 256 + threadIdx.x;
  int base = gi & ~(N_ - 1);
  float xi[64];
#pragma unroll
  for (int q = 0; q < 16; q++) {
    float4 v = reinterpret_cast<const float4*>(h1)[gi * 16 + q];
    xi[q * 4] = v.x; xi[q * 4 + 1] = v.y; xi[q * 4 + 2] = v.z; xi[q * 4 + 3] = v.w;
  }
  float x2i = x2h[gi];
  float idi = invdeg[gi];
  int cnt = ecnt[gi];
  const unsigned short* e = E + (size_t)gi * ECAP;
  unsigned* crow = cw + (size_t)gi * ECAP;
#pragma unroll 1
  for (int n = 0; n < cnt; n++) {
    int j = base + e[n];
    const float4* r = reinterpret_cast<const float4*>(h1 + (size_t)j * 64);
    float dot = 0.f;
#pragma unroll
    for (int q = 0; q < 16; q++) {
      float4 v = r[q];
      dot += xi[q * 4] * v.x + xi[q * 4 + 1] * v.y + xi[q * 4 + 2] * v.z + xi[q * 4 + 3] * v.w;
    }
    float d2 = fmaxf(x2i + x2h[j] - 2.f * dot, 0.f);
    float wgt = sqrtf(d2) * (idi + invdeg[j]);
    crow[n] = __float_as_uint(wgt);   // wgt >= 0 -> bit order == numeric order
  }
}

// ---------------------------------------------------------------- candidate sort
// One wave per node: bitonic-sort the 128 candidate slots DESCENDING by key
// (w<<32)|~j in registers (2 elems/lane, shfl_xor network), rewrite E in sorted
// order. Unused slots key=0 -> sort to the end, decode to 0xFFFF sentinel.
__global__ __launch_bounds__(256) void k_sort(
    const unsigned* __restrict__ cw, const unsigned short* __restrict__ E0,
    const int* __restrict__ ecnt, unsigned short* __restrict__ E)
{
  int node = (blockIdx.x * 256 + threadIdx.x) >> 6;
  int lane = threadIdx.x & 63;
  int cnt = ecnt[node];
  size_t rb = (size_t)node * ECAP;
  unsigned long long a = 0ull, b = 0ull;
  if (lane < cnt)
    a = ((unsigned long long)cw[rb + lane] << 32) | (unsigned)(~(unsigned)E0[rb + lane]);
  if (lane + 64 < cnt)
    b = ((unsigned long long)cw[rb + 64 + lane] << 32) | (unsigned)(~(unsigned)E0[rb + 64 + lane]);
#pragma unroll
  for (int k = 2; k <= 128; k <<= 1) {
#pragma unroll
    for (int jj = k >> 1; jj > 0; jj >>= 1) {
      if (jj == 64) {                         // partner = same lane's other element (k==128: desc)
        unsigned long long mx = a > b ? a : b;
        b = a > b ? b : a;
        a = mx;
      } else {
        unsigned long long oa = __shfl_xor(a, jj, 64);
        bool low   = (lane & jj) == 0;
        bool descA = (lane & k) == 0;
        a = ((low == descA) == (a > oa)) ? a : oa;
        unsigned long long ob = __shfl_xor(b, jj, 64);
        bool descB = (((lane + 64) & k) == 0);
        b = ((low == descB) == (b > ob)) ? b : ob;
      }
    }
  }
  E[rb + lane]      = (unsigned short)(~(unsigned)a);
  E[rb + 64 + lane] = (unsigned short)(~(unsigned)b);
}

// ---------------------------------------------------------------- graclus matching
// One wave per graph; sequential over i. Unmatched set = 1024-bit mask in VGPRs
// (16 bits/lane). Results buffered in LDS (res[n] = partner<<16 | cluster) and
// flushed AFTER the loop -> no global stores in the serial loop, so the compiler
// emits counted vmcnt waits for the 4-row register prefetch (R6: in-loop stores
// forced vmcnt(0) drains at ~595 cy/step).
__global__ __launch_bounds__(64) void k_graclus(
    const unsigned short* __restrict__ E,
    int* __restrict__ cluster, int* __restrict__ partner)
{
  __shared__ unsigned res[N_];   // low16 = cluster rep, high16 = partner (0xFFFF = none)
  int b = blockIdx.x, lane = threadIdx.x;
  int g0 = b * N_;
  const unsigned short* Eg = E + (size_t)g0 * ECAP;
  for (int t = lane; t < N_; t += 64) res[t] = 0xFFFF0000u | (unsigned)t;
  unsigned m16 = 0xFFFFu;                       // all 16 nodes of this lane unmatched

  unsigned short eA0, eA1, eB0, eB1, eC0, eC1, eD0, eD1;
#define LOADROW(E0v, E1v, row)                                                  \
  { size_t rb_ = (size_t)(row) * ECAP;                                          \
    E0v = Eg[rb_ + lane];                                                       \
    E1v = Eg[rb_ + 64 + lane]; }
  LOADROW(eA0, eA1, 0)
  LOADROW(eB0, eB1, 1)
  LOADROW(eC0, eC1, 2)
  LOADROW(eD0, eD1, 3)

  auto step = [&](int i, unsigned short e0, unsigned short e1) {
    unsigned mi = (unsigned)__builtin_amdgcn_readlane((int)m16, i >> 4);
    if ((mi >> (i & 15)) & 1u) {                // uniform branch: skip matched i
      bool v0 = e0 != 0xFFFFu, v1 = e1 != 0xFFFFu;
      int j0 = e0 & (N_ - 1), j1 = e1 & (N_ - 1);
      unsigned gm0 = (unsigned)__shfl((int)m16, j0 >> 4, 64);
      unsigned gm1 = (unsigned)__shfl((int)m16, j1 >> 4, 64);
      bool p0 = v0 && ((gm0 >> (j0 & 15)) & 1u);
      bool p1 = v1 && ((gm1 >> (j1 & 15)) & 1u);
      unsigned long long m0 = __ballot(p0);
      unsigned long long m1 = __ballot(p1);
      unsigned long long mm = m0 ? m0 : m1;
      if (mm) {                                 // uniform
        int sw = __ffsll((long long)mm) - 1;
        int jw = m0 ? __builtin_amdgcn_readlane(j0, sw)
                    : __builtin_amdgcn_readlane(j1, sw);
        m16 &= ~((lane == (jw >> 4)) ? (1u << (jw & 15)) : 0u);
        if (lane == 0) {
          int r = i < jw ? i : jw;
          int o = i ^ jw ^ r;
          res[o] = 0xFFFF0000u | (unsigned)r;           // o -> rep r, no partner
          res[r] = ((unsigned)o << 16) | (unsigned)r;   // r -> rep r, partner o
        }
      }
      m16 &= ~((lane == (i >> 4)) ? (1u << (i & 15)) : 0u);
    }
  };

  for (int i = 0; i < N_; i += 4) {
    step(i, eA0, eA1);
    if (i + 4 < N_) LOADROW(eA0, eA1, i + 4)
    step(i + 1, eB0, eB1);
    if (i + 5 < N_) LOADROW(eB0, eB1, i + 5)
    step(i + 2, eC0, eC1);
    if (i + 6 < N_) LOADROW(eC0, eC1, i + 6)
    step(i + 3, eD0, eD1);
    if (i + 7 < N_) LOADROW(eD0, eD1, i + 7)
  }
#undef LOADROW
  __syncthreads();
  for (int t = lane; t < N_; t += 64) {
    unsigned v = res[t];
    cluster[g0 + t] = (int)(v & 0xFFFFu);
    int p = (int)(v >> 16);
    partner[g0 + t] = (p == 0xFFFF) ? -1 : p;
  }
}

// ---------------------------------------------------------------- max pool
__global__ __launch_bounds__(256) void k_maxpool(
    const float* __restrict__ h1, const int* __restrict__ cluster, const int* __restrict__ partner,
    float* __restrict__ h1p, float* __restrict__ x2p, int* __restrict__ valid1,
    unsigned* __restrict__ vbits)
{
  int gi = blockIdx.x * 256 + threadIdx.x;
  int b = gi >> 10, i = gi & 1023;
  if (cluster[gi] == i) {
    int p = partner[gi];
    float s = 0.f;
#pragma unroll
    for (int q = 0; q < 16; q++) {
      float4 a = reinterpret_cast<const float4*>(h1)[gi * 16 + q];
      if (p >= 0) {
        float4 c = reinterpret_cast<const float4*>(h1)[(b * N_ + p) * 16 + q];
        a.x = fmaxf(a.x, c.x); a.y = fmaxf(a.y, c.y); a.z = fmaxf(a.z, c.z); a.w = fmaxf(a.w, c.w);
      }
      reinterpret_cast<float4*>(h1p)[gi * 16 + q] = a;
      s += a.x * a.x + a.y * a.y + a.z * a.z + a.w * a.w;
    }
    x2p[gi] = s; valid1[gi] = 1;
    atomicOr(&vbits[b * 32 + (i >> 5)], 1u << (i & 31));
  } else {
    float4 z = make_float4(0.f, 0.f, 0.f, 0.f);
#pragma unroll
    for (int q = 0; q < 16; q++) reinterpret_cast<float4*>(h1p)[gi * 16 + q] = z;
    x2p[gi] = 0.f; valid1[gi] = 0;
  }
}

// ---------------------------------------------------------------- global max + out MLP
__global__ __launch_bounds__(256) void k_final(
    const float* __restrict__ h2, const int* __restrict__ valid1,
    const float* __restrict__ o1W, const float* __restrict__ o1b,
    const float* __restrict__ o2W, const float* __restrict__ o2b,
    const float* __restrict__ o3W, const float* __restrict__ o3b,
    float* __restrict__ out)
{
  __shared__ float gm[4][64], g[64], l1[64], l2[32];
  int b = blockIdx.x, tid = threadIdx.x;
  int d = tid & 63, r = tid >> 6;
  float m = -INFF;
  for (int i = r; i < N_; i += 4) {
    if (valid1[b * N_ + i]) m = fmaxf(m, h2[(size_t)(b * N_ + i) * 64 + d]);
  }
  gm[r][d] = m;
  __syncthreads();
  if (tid < 64) g[d] = fmaxf(fmaxf(gm[0][d], gm[1][d]), fmaxf(gm[2][d], gm[3][d]));
  __syncthreads();
  if (tid < 64) {
    float a = o1b[tid];
    for (int c = 0; c < 64; c++) a += g[c] * o1W[c * 64 + tid];
    l1[tid] = elu_(a);
  }
  __syncthreads();
  if (tid < 32) {
    float a2 = o2b[tid];
    for (int c = 0; c < 64; c++) a2 += l1[c] * o2W[c * 32 + tid];
    l2[tid] = elu_(a2);
  }
  __syncthreads();
  if (tid < 2) {
    float a3 = o3b[tid];
    for (int c = 0; c < 32; c++) a3 += l2[c] * o3W[c * 2 + tid];
    out[b * 2 + tid] = a3;
  }
}

// ---------------------------------------------------------------- launch
extern "C" void kernel_launch(void* const* d_in, const int* in_sizes, int n_in,
                              void* d_out, int out_size, void* d_ws, size_t ws_size,
                              hipStream_t stream)
{
  const float* x    = (const float*)d_in[0];
  const float* nrm  = (const float*)d_in[1];
  const float* in1W = (const float*)d_in[2];  const float* in1b = (const float*)d_in[3];
  const float* in2W = (const float*)d_in[4];  const float* in2b = (const float*)d_in[5];
  const float* in3W = (const float*)d_in[6];  const float* in3b = (const float*)d_in[7];
  const float* c1aW = (const float*)d_in[8];  const float* c1ab = (const float*)d_in[9];
  const float* c1bW = (const float*)d_in[10]; const float* c1bb = (const float*)d_in[11];
  const float* c2aW = (const float*)d_in[12]; const float* c2ab = (const float*)d_in[13];
  const float* c2bW = (const float*)d_in[14]; const float* c2bb = (const float*)d_in[15];
  const float* o1W  = (const float*)d_in[16]; const float* o1b  = (const float*)d_in[17];
  const float* o2W  = (const float*)d_in[18]; const float* o2b  = (const float*)d_in[19];
  const float* o3W  = (const float*)d_in[20]; const float* o3b  = (const float*)d_in[21];

  // workspace layout. O_U is a union region with three disjoint-lifetime tenants:
  //   {pd 16MB + pix 8MB} (knn->merge)  |  {wb 12MB + vb 12MB} (uv->conv)  |  {cw 16MB} (wgt->sort)
  // h1p overlays h0; h2 overlays h1; E persists from elist1 through graclus (sorted in place
  // region), rewritten at elist2. perm rebuilt per stage after its k_elist.
  constexpr size_t O_H0    = 0;                                   // h0 | h1p  (8 MB)
  constexpr size_t O_X2A   = O_H0    + (size_t)NN * 64 * 4;       // x2a | x2p
  constexpr size_t O_U     = O_X2A   + (size_t)NN * 4;            // union (24 MB)
  constexpr size_t O_K     = O_U     + (size_t)NN * NCH * 16 * 6; // K bitmask (4 MB)
  constexpr size_t O_KT    = O_K     + (size_t)NN * 32 * 4;       // KT bitmask (4 MB, contiguous after K)
  constexpr size_t O_H1    = O_KT    + (size_t)NN * 32 * 4;       // h1 | h2 (8 MB)
  constexpr size_t O_X2H   = O_H1    + (size_t)NN * 64 * 4;
  constexpr size_t O_IDG   = O_X2H   + (size_t)NN * 4;
  constexpr size_t O_ECNT  = O_IDG   + (size_t)NN * 4;
  constexpr size_t O_CLU   = O_ECNT  + (size_t)NN * 4;
  constexpr size_t O_PAR   = O_CLU   + (size_t)NN * 4;
  constexpr size_t O_VAL   = O_PAR   + (size_t)NN * 4;
  constexpr size_t O_VBITS = O_VAL   + (size_t)NN * 4;
  constexpr size_t O_E     = O_VBITS + (size_t)B_ * 32 * 4;       // edge list (8 MB)
  constexpr size_t O_PERM  = O_E     + (size_t)NN * ECAP * 2;     // degree perm (64 KB)
  constexpr size_t TOTAL   = O_PERM  + (size_t)NN * 2;            // ~57 MB
  if (ws_size < TOTAL) return;

  char* w = (char*)d_ws;
  float*          h0   = (float*)(w + O_H0);
  float*          x2a  = (float*)(w + O_X2A);
  float*          pdp  = (float*)(w + O_U);
  unsigned short* pip  = (unsigned short*)(w + O_U + (size_t)NN * NCH * 16 * 4);
  float*          wb   = (float*)(w + O_U);
  float*          vb   = (float*)(w + O_U + (size_t)NN * 96 * 4);
  unsigned*       cwt  = (unsigned*)(w + O_U);
  unsigned*       Kb   = (unsigned*)(w + O_K);
  unsigned*       KTb  = (unsigned*)(w + O_KT);
  float*          h1   = (float*)(w + O_H1);
  float*          x2h  = (float*)(w + O_X2H);
  float*          idg  = (float*)(w + O_IDG);
  int*            ecnt = (int*)(w + O_ECNT);
  int*            clu  = (int*)(w + O_CLU);
  int*            par  = (int*)(w + O_PAR);
  int*            val  = (int*)(w + O_VAL);
  unsigned*       vbits= (unsigned*)(w + O_VBITS);
  unsigned short* E    = (unsigned short*)(w + O_E);
  unsigned short* perm = (unsigned short*)(w + O_PERM);
  float* h1p = h0;
  float* x2p = x2a;
  float* h2  = h1;

  // ---- stage 1 (all nodes valid)
  k_input<<<NN / 256, 256, 0, stream>>>(x, nrm, in1W, in1b, in2W, in2b, in3W, in3b, h0, x2a);
  k_knn<<<B_ * 32, 256, 0, stream>>>((const float4*)h0, x2a, nullptr, nullptr, pdp, pip);
  hipMemsetAsync(KTb, 0, (size_t)NN * 32 * 4, stream);
  k_merge<<<NN / 64, 64, 0, stream>>>(pdp, pip, nullptr, Kb, KTb);
  k_elist<<<NN / 256, 256, 0, stream>>>(Kb, KTb, E, ecnt, idg);
  k_perm<<<B_, 256, 0, stream>>>(ecnt, perm);
  k_uv<<<NN / 256, 256, 0, stream>>>(h0, c1aW, c1ab, wb, vb);
  k_conv<<<NN / 64, 256, 0, stream>>>(wb, vb, E, ecnt, perm, c1bW, c1bb, h1, x2h);
  // ---- graclus + pool
  k_wgt<<<NN / 256, 256, 0, stream>>>(h1, x2h, idg, E, ecnt, cwt);
  k_sort<<<NN / 4, 256, 0, stream>>>(cwt, E, ecnt, E);
  k_graclus<<<B_, 64, 0, stream>>>(E, clu, par);
  hipMemsetAsync(vbits, 0, (size_t)B_ * 32 * 4, stream);
  k_maxpool<<<NN / 256, 256, 0, stream>>>(h1, clu, par, h1p, x2p, val, vbits);
  // ---- stage 2 (valid = cluster representatives; invalid rows have ecnt==0)
  k_knn<<<B_ * 32, 256, 0, stream>>>((const float4*)h1p, x2p, vbits, val, pdp, pip);
  hipMemsetAsync(Kb, 0, (size_t)NN * 32 * 4 * 2, stream);   // K and KT, contiguous
  k_merge<<<NN / 64, 64, 0, stream>>>(pdp, pip, val, Kb, KTb);
  k_elist<<<NN / 256, 256, 0, stream>>>(Kb, KTb, E, ecnt, nullptr);
  k_perm<<<B_, 256, 0, stream>>>(ecnt, perm);
  k_uv<<<NN / 256, 256, 0, stream>>>(h1p, c2aW, c2ab, wb, vb);
  k_conv<<<NN / 64, 256, 0, stream>>>(wb, vb, E, ecnt, perm, c2bW, c2bb, h2, nullptr);
  k_final<<<B_, 256, 0, stream>>>(h2, val, o1W, o1b, o2W, o2b, o3W, o3b, (float*)d_out);
}

// Round 9
// 1499.664 us; speedup vs baseline: 1.3046x; 1.0828x over previous
//
#include <hip/hip_runtime.h>
#include <cmath>

// DynamicReductionNetwork forward on MI355X. All f32 (no fp32 MFMA -> vector ALU).
// input MLP -> kNN16 -> EdgeConv -> graclus -> maxpool -> kNN16 -> EdgeConv -> global max -> MLP.
// EdgeConv identity: message at dst i from source s (fwd or rev, deduped) = MLP2(elu(wb[i]+vb[s])),
// summed over the undirected neighbor set K|KT. One edge list serves conv AND graclus.
// R8 lesson: graclus flat at ~590 cy/step; FETCH 4.1MB/8MB -> half the E-rows come from HBM
// (~900cy) and the 4-deep 2-load/row prefetch only covered ~600cy. R9: k_sort packs each row
// into 64 dwords (1 load/row/lane) and graclus keeps a 16-deep register rotation in flight.

#define DEVI __device__ __forceinline__
constexpr int B_   = 32;
constexpr int N_   = 1024;
constexpr int NN   = B_ * N_;    // 32768 nodes
constexpr int NCH  = 8;          // knn column chunks
constexpr int CHW  = 128;        // columns per chunk
constexpr int ECAP = 128;        // edge-list cap per node (deg = 16 + in-deg)

#define INFF (__builtin_huge_valf())

DEVI float elu_(float x)  { return x > 0.f ? x : expm1f(x); }          // exact-ish (cheap kernels)
DEVI float eluf(float x)  { return x > 0.f ? x : __expf(x) - 1.f; }    // fast (conv hot loop)

// ---------------------------------------------------------------- input MLP
__global__ __launch_bounds__(256) void k_input(
    const float* __restrict__ x, const float* __restrict__ nrm,
    const float* __restrict__ w1, const float* __restrict__ b1,
    const float* __restrict__ w2, const float* __restrict__ b2,
    const float* __restrict__ w3, const float* __restrict__ b3,
    float* __restrict__ h0, float* __restrict__ x2a)
{
  __shared__ float s1[128], sb1[32], s2[2048], sb2[64], s3[4096], sb3[64];
  int tid = threadIdx.x;
  for (int t = tid; t < 128; t += 256) s1[t] = w1[t];
  if (tid < 32) sb1[tid] = b1[tid];
  for (int t = tid; t < 2048; t += 256) s2[t] = w2[t];
  if (tid < 64) sb2[tid] = b2[tid];
  for (int t = tid; t < 4096; t += 256) s3[t] = w3[t];
  if (tid < 64) sb3[tid] = b3[tid];
  __syncthreads();
  int n = blockIdx.x * 256 + tid;
  float xi[4];
#pragma unroll
  for (int d = 0; d < 4; d++) xi[d] = x[n * 4 + d] * nrm[d];
  float a1[32];
#pragma unroll
  for (int c = 0; c < 32; c++) {
    float a = sb1[c];
#pragma unroll
    for (int d = 0; d < 4; d++) a += xi[d] * s1[d * 32 + c];
    a1[c] = elu_(a);
  }
  float a2[64];
#pragma unroll
  for (int c = 0; c < 64; c++) {
    float a = sb2[c];
#pragma unroll
    for (int d = 0; d < 32; d++) a += a1[d] * s2[d * 64 + c];
    a2[c] = elu_(a);
  }
  float ss = 0.f;
#pragma unroll
  for (int c = 0; c < 64; c++) {
    float a = sb3[c];
#pragma unroll
    for (int d = 0; d < 64; d++) a += a2[d] * s3[d * 64 + c];
    a = elu_(a);
    h0[n * 64 + c] = a;
    ss += a * a;
  }
  x2a[n] = ss;
}

// ---------------------------------------------------------------- kNN partials
// per (graph, 256-row tile, 128-col chunk): per-thread sorted top-16 (d2 asc, tie -> smaller j).
__global__ __launch_bounds__(256) void k_knn(
    const float4* __restrict__ X4, const float* __restrict__ X2,
    const unsigned* __restrict__ vbits, const int* __restrict__ vrows,
    float* __restrict__ pd, unsigned short* __restrict__ pix)
{
  __shared__ float xs[CHW * 64];
  __shared__ float xs2[CHW];
  __shared__ unsigned vm[32];
  int bid = blockIdx.x;
  int swz = (bid & 7) * 128 + (bid >> 3);   // XCD swizzle (1024 blocks, %8==0 -> bijective)
  int b  = swz >> 5;
  int rt = (swz >> 3) & 3;
  int ch = swz & 7;
  int tid = threadIdx.x;
  int j0 = ch * CHW;
  for (int t = tid; t < CHW * 16; t += 256) {
    int r = t >> 4, q = t & 15;
    float4 v = X4[(b * N_ + j0 + r) * 16 + q];
    *reinterpret_cast<float4*>(&xs[r * 64 + q * 4]) = v;
  }
  for (int t = tid; t < CHW; t += 256) xs2[t] = X2[b * N_ + j0 + t];
  for (int t = tid; t < 32; t += 256) vm[t] = vbits ? vbits[b * 32 + t] : 0xFFFFFFFFu;
  __syncthreads();
  int i = rt * 256 + tid;
  int gi = b * N_ + i;
  if (vrows && !vrows[gi]) return;
  float4 xi4[16];
#pragma unroll
  for (int q = 0; q < 16; q++) xi4[q] = X4[gi * 16 + q];
  float x2i = X2[gi];
  float topd[16]; int topi[16];
#pragma unroll
  for (int q = 0; q < 16; q++) { topd[q] = INFF; topi[q] = 0xFFFF; }
  for (int jj = 0; jj < CHW; ++jj) {
    int j = j0 + jj;
    if (j == i) continue;
    if (!((vm[j >> 5] >> (j & 31)) & 1u)) continue;
    const float4* xr = reinterpret_cast<const float4*>(&xs[jj * 64]);  // b128, uniform addr -> broadcast
    float dot = 0.f;
#pragma unroll
    for (int q = 0; q < 16; q++) {
      float4 v = xr[q];
      dot += xi4[q].x * v.x + xi4[q].y * v.y + xi4[q].z * v.z + xi4[q].w * v.w;
    }
    float d2 = fmaxf(x2i + xs2[jj] - 2.f * dot, 0.f);
    if (d2 < topd[15]) {            // strict: equal keeps earlier (smaller j)
      topd[15] = d2; topi[15] = j;
#pragma unroll
      for (int p = 15; p > 0; --p) {
        if (topd[p] < topd[p - 1]) {
          float td = topd[p]; topd[p] = topd[p - 1]; topd[p - 1] = td;
          int   ti = topi[p]; topi[p] = topi[p - 1]; topi[p - 1] = ti;
        }
      }
    }
  }
  size_t base = ((size_t)gi * NCH + ch) * 16;
#pragma unroll
  for (int q = 0; q < 16; q++) { pd[base + q] = topd[q]; pix[base + q] = (unsigned short)topi[q]; }
}

// ---------------------------------------------------------------- kNN merge
// top-16 over 8 sorted partials; writes dense row bitmask K and transposed KT (atomicOr, pre-zeroed).
__global__ __launch_bounds__(64) void k_merge(
    const float* __restrict__ pd, const unsigned short* __restrict__ pix,
    const int* __restrict__ vrows,
    unsigned* __restrict__ Kb, unsigned* __restrict__ KTb)
{
  __shared__ unsigned lbm[64][33];   // 8.4 KB; per-thread row, no cross-thread use
  int tid = threadIdx.x;
  int gi = blockIdx.x * 64 + tid;
  int b = gi >> 10, i = gi & 1023;
  if (vrows && !vrows[gi]) return;
#pragma unroll
  for (int w = 0; w < 32; w++) lbm[tid][w] = 0u;
  float topd[16]; int topi[16];
#pragma unroll
  for (int q = 0; q < 16; q++) { topd[q] = INFF; topi[q] = 0; }
  for (int s = 0; s < NCH; ++s) {
    size_t base = ((size_t)gi * NCH + s) * 16;
#pragma unroll 1
    for (int q = 0; q < 16; q++) {
      float d = pd[base + q];
      if (!(d < topd[15])) break;   // partial ascending -> rest rejected too
      topd[15] = d; topi[15] = pix[base + q];
#pragma unroll
      for (int p = 15; p > 0; --p) {
        if (topd[p] < topd[p - 1]) {
          float td = topd[p]; topd[p] = topd[p - 1]; topd[p - 1] = td;
          int   ti = topi[p]; topi[p] = topi[p - 1]; topi[p - 1] = ti;
        }
      }
    }
  }
#pragma unroll
  for (int q = 0; q < 16; q++) {
    int j = topi[q];
    lbm[tid][j >> 5] |= (1u << (j & 31));
    atomicOr(&KTb[((size_t)b * N_ + j) * 32 + (i >> 5)], 1u << (i & 31));
  }
#pragma unroll
  for (int w = 0; w < 32; w++) Kb[(size_t)gi * 32 + w] = lbm[tid][w];
}

// ---------------------------------------------------------------- edge list (undirected K|KT row)
__global__ __launch_bounds__(256) void k_elist(
    const unsigned* __restrict__ Kb, const unsigned* __restrict__ KTb,
    unsigned short* __restrict__ E, int* __restrict__ ecnt, float* __restrict__ invdeg)
{
  int gi = blockIdx.x * 256 + threadIdx.x;
  unsigned short* e = E + (size_t)gi * ECAP;
  int n = 0;
  for (int w = 0; w < 32; w++) {
    unsigned m = Kb[(size_t)gi * 32 + w] | KTb[(size_t)gi * 32 + w];
    while (m) {
      int bit = __ffs(m) - 1; m &= m - 1;
      if (n < ECAP) e[n] = (unsigned short)(w * 32 + bit);
      n++;
    }
  }
  ecnt[gi] = n < ECAP ? n : ECAP;
  if (invdeg) invdeg[gi] = 1.f / (float)n;   // true degree (matches A.sum(-1))
}

// ---------------------------------------------------------------- degree permutation
// per graph: counting-sort node ids by ecnt ascending -> perm. Used by k_conv so
// each wave's 16 dsts have uniform edge counts (kills masked-lane divergence) and
// blocks get balanced heavy+light wave-group sets.
__global__ __launch_bounds__(256) void k_perm(
    const int* __restrict__ ecnt, unsigned short* __restrict__ perm)
{
  __shared__ int hist[ECAP + 1];
  __shared__ int pfx[ECAP + 1];
  int b = blockIdx.x, tid = threadIdx.x;
  int g0 = b * N_;
  for (int t = tid; t <= ECAP; t += 256) hist[t] = 0;
  __syncthreads();
  for (int t = tid; t < N_; t += 256) atomicAdd(&hist[ecnt[g0 + t]], 1);
  __syncthreads();
  if (tid == 0) {
    int s = 0;
    for (int d = 0; d <= ECAP; d++) { pfx[d] = s; s += hist[d]; }
  }
  __syncthreads();
  for (int t = tid; t < N_; t += 256) {
    int r = atomicAdd(&pfx[ecnt[g0 + t]], 1);
    perm[g0 + r] = (unsigned short)t;
  }
}

// ---------------------------------------------------------------- edge MLP precompute
// wb = x@(W1[:64]-W1[64:]) + b1 ; vb = x@W1[64:]  (per-edge layer1 = wb_dst + vb_src)
__global__ __launch_bounds__(256) void k_uv(
    const float* __restrict__ X, const float* __restrict__ W1, const float* __restrict__ b1,
    float* __restrict__ wb, float* __restrict__ vb)
{
  __shared__ float wc[64 * 96], wv[64 * 96];
  int tid = threadIdx.x;
  for (int t = tid; t < 64 * 96; t += 256) {
    int d = t / 96, c = t - d * 96;
    float hv = W1[(d + 64) * 96 + c];
    wv[t] = hv;
    wc[t] = W1[d * 96 + c] - hv;
  }
  __syncthreads();
  int n = blockIdx.x * 256 + tid;
  float xi[64];
#pragma unroll
  for (int q = 0; q < 16; q++) {
    float4 v = reinterpret_cast<const float4*>(X)[n * 16 + q];
    xi[q * 4] = v.x; xi[q * 4 + 1] = v.y; xi[q * 4 + 2] = v.z; xi[q * 4 + 3] = v.w;
  }
#pragma unroll 1
  for (int c4 = 0; c4 < 24; c4++) {
    float aw0 = b1[c4 * 4 + 0], aw1 = b1[c4 * 4 + 1], aw2 = b1[c4 * 4 + 2], aw3 = b1[c4 * 4 + 3];
    float av0 = 0.f, av1 = 0.f, av2 = 0.f, av3 = 0.f;
#pragma unroll
    for (int d = 0; d < 64; d++) {
      float4 c = *reinterpret_cast<const float4*>(&wc[d * 96 + c4 * 4]);
      float4 v = *reinterpret_cast<const float4*>(&wv[d * 96 + c4 * 4]);
      float xd = xi[d];
      aw0 += xd * c.x; aw1 += xd * c.y; aw2 += xd * c.z; aw3 += xd * c.w;
      av0 += xd * v.x; av1 += xd * v.y; av2 += xd * v.z; av3 += xd * v.w;
    }
    wb[(size_t)n * 96 + c4 * 4 + 0] = aw0; wb[(size_t)n * 96 + c4 * 4 + 1] = aw1;
    wb[(size_t)n * 96 + c4 * 4 + 2] = aw2; wb[(size_t)n * 96 + c4 * 4 + 3] = aw3;
    vb[(size_t)n * 96 + c4 * 4 + 0] = av0; vb[(size_t)n * 96 + c4 * 4 + 1] = av1;
    vb[(size_t)n * 96 + c4 * 4 + 2] = av2; vb[(size_t)n * 96 + c4 * 4 + 3] = av3;
  }
}

// ---------------------------------------------------------------- EdgeConv
// 4 lanes per dst, each owns a 16-wide output slice. Dsts assigned via degree-sorted
// perm: wave w of block kk handles sorted wave-group {kk,31-kk,32+kk,63-kk}[w]
// (uniform cnt within wave, balanced totals across blocks). cnt==0 rows (stage-2
// invalid) write zeros. Edge-pair unroll shares each w2s LDS read across 8 FMAs;
// c4-loop unrolled 4x to batch the vbuf L2 loads.
__global__ __launch_bounds__(256) void k_conv(
    const float* __restrict__ wbuf, const float* __restrict__ vbuf,
    const unsigned short* __restrict__ E, const int* __restrict__ ecnt,
    const unsigned short* __restrict__ perm,
    const float* __restrict__ W2, const float* __restrict__ b2,
    float* __restrict__ out, float* __restrict__ x2out)
{
  __shared__ float w2s[96 * 64];
  __shared__ float b2s[64];
  __shared__ float wds[64 * 100];   // pad 100: dl*100 stride -> 2-way banks (free per m136)
  __shared__ unsigned short dstl[64];
  int tid = threadIdx.x;
  int bid = blockIdx.x;
  int swz = (bid & 7) * 64 + (bid >> 3);   // XCD swizzle: each XCD -> 4 contiguous graphs
  int g  = swz >> 4, kk = swz & 15;
  int gb = g * N_;
  for (int t = tid; t < 96 * 64; t += 256) w2s[t] = W2[t];
  if (tid < 64) b2s[tid] = b2[tid];
  if (tid < 64) {
    int w = tid >> 4, r = tid & 15;
    int wg = (w == 0) ? kk : (w == 1) ? 31 - kk : (w == 2) ? 32 + kk : 63 - kk;
    dstl[tid] = perm[gb + wg * 16 + r];
  }
  __syncthreads();
  for (int t = tid; t < 64 * 96; t += 256) {
    int l = t / 96, c = t - l * 96;
    wds[l * 100 + c] = wbuf[(size_t)(gb + dstl[l]) * 96 + c];
  }
  __syncthreads();
  int dl = tid >> 2, p = tid & 3;
  int dst = gb + dstl[dl];
  int cnt = ecnt[dst];
  const unsigned short* e = E + (size_t)dst * ECAP;
  float agg[16];
#pragma unroll
  for (int o = 0; o < 16; o++) agg[o] = 0.f;

#pragma unroll 1
  for (int k = 0; k < cnt; k += 2) {
    bool hasB = (k + 1 < cnt);
    int sA = gb + e[k];
    int sB = hasB ? gb + e[k + 1] : sA;
    const float4* vA = reinterpret_cast<const float4*>(vbuf + (size_t)sA * 96);
    const float4* vB = reinterpret_cast<const float4*>(vbuf + (size_t)sB * 96);
    float sa[16], sb_[16];
#pragma unroll
    for (int o = 0; o < 16; o++) { sa[o] = b2s[p * 16 + o]; sb_[o] = sa[o]; }
#pragma unroll 4
    for (int c4 = 0; c4 < 24; c4++) {
      float4 wv = *reinterpret_cast<const float4*>(&wds[dl * 100 + c4 * 4]);
      float4 a4 = vA[c4];
      float4 b4 = vB[c4];
      float tA0 = eluf(wv.x + a4.x), tA1 = eluf(wv.y + a4.y),
            tA2 = eluf(wv.z + a4.z), tA3 = eluf(wv.w + a4.w);
      float tB0 = eluf(wv.x + b4.x), tB1 = eluf(wv.y + b4.y),
            tB2 = eluf(wv.z + b4.z), tB3 = eluf(wv.w + b4.w);
      const float* wr = &w2s[(c4 * 4) * 64 + p * 16];
#pragma unroll
      for (int o4 = 0; o4 < 4; o4++) {
        float4 w0 = *reinterpret_cast<const float4*>(wr + 0 * 64 + o4 * 4);
        float4 w1 = *reinterpret_cast<const float4*>(wr + 1 * 64 + o4 * 4);
        float4 w2 = *reinterpret_cast<const float4*>(wr + 2 * 64 + o4 * 4);
        float4 w3 = *reinterpret_cast<const float4*>(wr + 3 * 64 + o4 * 4);
        sa [o4*4+0] += tA0*w0.x + tA1*w1.x + tA2*w2.x + tA3*w3.x;
        sa [o4*4+1] += tA0*w0.y + tA1*w1.y + tA2*w2.y + tA3*w3.y;
        sa [o4*4+2] += tA0*w0.z + tA1*w1.z + tA2*w2.z + tA3*w3.z;
        sa [o4*4+3] += tA0*w0.w + tA1*w1.w + tA2*w2.w + tA3*w3.w;
        sb_[o4*4+0] += tB0*w0.x + tB1*w1.x + tB2*w2.x + tB3*w3.x;
        sb_[o4*4+1] += tB0*w0.y + tB1*w1.y + tB2*w2.y + tB3*w3.y;
        sb_[o4*4+2] += tB0*w0.z + tB1*w1.z + tB2*w2.z + tB3*w3.z;
        sb_[o4*4+3] += tB0*w0.w + tB1*w1.w + tB2*w2.w + tB3*w3.w;
      }
    }
#pragma unroll
    for (int o = 0; o < 16; o++) agg[o] += eluf(sa[o]);
    if (hasB) {
#pragma unroll
      for (int o = 0; o < 16; o++) agg[o] += eluf(sb_[o]);
    }
  }
  float4* o4p = reinterpret_cast<float4*>(out + (size_t)dst * 64 + p * 16);
#pragma unroll
  for (int q = 0; q < 4; q++)
    o4p[q] = make_float4(agg[q*4], agg[q*4+1], agg[q*4+2], agg[q*4+3]);
  if (x2out) {
    float s = 0.f;
#pragma unroll
    for (int o = 0; o < 16; o++) s += agg[o] * agg[o];
    s += __shfl_xor(s, 1, 64);
    s += __shfl_xor(s, 2, 64);
    if (p == 0) x2out[dst] = s;
  }
}

// ---------------------------------------------------------------- graclus edge weights
// cw[gi][n] = bits( ||h1_i-h1_j|| * (invdeg_i+invdeg_j) ) for j = E[gi][n].
__global__ __launch_bounds__(256) void k_wgt(
    const float* __restrict__ h1, const float* __restrict__ x2h,
    const float* __restrict__ invdeg, const unsigned short* __restrict__ E,
    const int* __restrict__ ecnt, unsigned* __restrict__ cw)
{
  int bid = blockIdx.x;
  int swz = (bid & 7) * 16 + (bid >> 3);
  int gi = swz * 256 + threadIdx.x;
  int base = gi & ~(N_ - 1);
  float xi[64];
#pragma unroll
  for (int q = 0; q < 16; q++) {
    float4 v = reinterpret_cast<const float4*>(h1)[gi * 16 + q];
    xi[q * 4] = v.x; xi[q * 4 + 1] = v.y; xi[q * 4 + 2] = v.z; xi[q * 4 + 3] = v.w;
  }
  float x2i = x2h[gi];
  float idi = invdeg[gi];
  int cnt = ecnt[gi];
  const unsigned short* e = E + (size_t)gi * ECAP;
  unsigned* crow = cw + (size_t)gi * ECAP;
#pragma unroll 1
  for (int n = 0; n < cnt; n++) {
    int j = base + e[n];
    const float4* r = reinterpret_cast<const float4*>(h1 + (size_t)j * 64);
    float dot = 0.f;
#pragma unroll
    for (int q = 0; q < 16; q++) {
      float4 v = r[q];
      dot += xi[q * 4] * v.x + xi[q * 4 + 1] * v.y + xi[q * 4 + 2] * v.z + xi[q * 4 + 3] * v.w;
    }
    float d2 = fmaxf(x2i + x2h[j] - 2.f * dot, 0.f);
    float wgt = sqrtf(d2) * (idi + invdeg[j]);
    crow[n] = __float_as_uint(wgt);   // wgt >= 0 -> bit order == numeric order
  }
}

// ---------------------------------------------------------------- candidate sort
// One wave per node: bitonic-sort the 128 candidate slots DESCENDING by key
// (w<<32)|~j in registers (2 elems/lane, shfl_xor network). Output is written
// INTERLEAVED as one dword per lane per row: low16 = slot[lane] (elems 0..63),
// high16 = slot[64+lane] -> graclus does ONE dword load per row per lane.
// Unused slots key=0 -> sort to the end, decode to 0xFFFF sentinel.
__global__ __launch_bounds__(256) void k_sort(
    const unsigned* __restrict__ cw, const unsigned short* __restrict__ E0,
    const int* __restrict__ ecnt, unsigned* __restrict__ EI)
{
  int node = (blockIdx.x * 256 + threadIdx.x) >> 6;
  int lane = threadIdx.x & 63;
  int cnt = ecnt[node];
  size_t rb = (size_t)node * ECAP;
  unsigned long long a = 0ull, b = 0ull;
  if (lane < cnt)
    a = ((unsigned long long)cw[rb + lane] << 32) | (unsigned)(~(unsigned)E0[rb + lane]);
  if (lane + 64 < cnt)
    b = ((unsigned long long)cw[rb + 64 + lane] << 32) | (unsigned)(~(unsigned)E0[rb + 64 + lane]);
#pragma unroll
  for (int k = 2; k <= 128; k <<= 1) {
#pragma unroll
    for (int jj = k >> 1; jj > 0; jj >>= 1) {
      if (jj == 64) {                         // partner = same lane's other element (k==128: desc)
        unsigned long long mx = a > b ? a : b;
        b = a > b ? b : a;
        a = mx;
      } else {
        unsigned long long oa = __shfl_xor(a, jj, 64);
        bool low   = (lane & jj) == 0;
        bool descA = (lane & k) == 0;
        a = ((low == descA) == (a > oa)) ? a : oa;
        unsigned long long ob = __shfl_xor(b, jj, 64);
        bool descB = (((lane + 64) & k) == 0);
        b = ((low == descB) == (b > ob)) ? b : ob;
      }
    }
  }
  unsigned lo = (unsigned)(~(unsigned)a) & 0xFFFFu;
  unsigned hi = (unsigned)(~(unsigned)b) & 0xFFFFu;
  EI[(size_t)node * 64 + lane] = (hi << 16) | lo;
}

// ---------------------------------------------------------------- graclus matching
// One wave per graph; sequential over i. Unmatched set = 1024-bit mask in VGPRs
// (16 bits/lane). Results buffered in LDS, flushed post-loop. E rows interleaved:
// ONE dword load per row per lane, 16-row register rotation (full-unrolled ->
// static indices, stays in VGPRs) => ~16 steps (~2200cy) of memory-latency
// coverage vs ~900cy HBM (R8: 4-deep x 2-load only covered ~600cy -> stalled).
// Rotation reloads read <=4KB past the last graph's rows: lands in the perm
// region of d_ws (never consumed, no fault).
__global__ __launch_bounds__(64) void k_graclus(
    const unsigned* __restrict__ EI,
    int* __restrict__ cluster, int* __restrict__ partner)
{
  __shared__ unsigned res[N_];   // low16 = cluster rep, high16 = partner (0xFFFF = none)
  int b = blockIdx.x, lane = threadIdx.x;
  int g0 = b * N_;
  const unsigned* Eg = EI + (size_t)g0 * 64;
  for (int t = lane; t < N_; t += 64) res[t] = 0xFFFF0000u | (unsigned)t;
  unsigned m16 = 0xFFFFu;                       // all 16 nodes of this lane unmatched

  unsigned rr[16];
#pragma unroll
  for (int w = 0; w < 16; w++) rr[w] = Eg[(size_t)w * 64 + lane];

  auto step = [&](int i, unsigned ed) {
    unsigned mi = (unsigned)__builtin_amdgcn_readlane((int)m16, i >> 4);
    if ((mi >> (i & 15)) & 1u) {                // uniform branch: skip matched i
      int j0 = (int)(ed & (N_ - 1));
      int j1 = (int)((ed >> 16) & (N_ - 1));
      bool v0 = (ed & 0xFFFFu) != 0xFFFFu;
      bool v1 = (ed >> 16) != 0xFFFFu;
      unsigned gm0 = (unsigned)__shfl((int)m16, j0 >> 4, 64);
      unsigned gm1 = (unsigned)__shfl((int)m16, j1 >> 4, 64);
      bool p0 = v0 && ((gm0 >> (j0 & 15)) & 1u);
      bool p1 = v1 && ((gm1 >> (j1 & 15)) & 1u);
      unsigned long long m0 = __ballot(p0);
      unsigned long long m1 = __ballot(p1);
      unsigned long long mm = m0 ? m0 : m1;
      if (mm) {                                 // uniform
        int sw = __ffsll((long long)mm) - 1;
        int jw = m0 ? __builtin_amdgcn_readlane(j0, sw)
                    : __builtin_amdgcn_readlane(j1, sw);
        m16 &= ~((lane == (jw >> 4)) ? (1u << (jw & 15)) : 0u);
        if (lane == 0) {
          int r = i < jw ? i : jw;
          int o = i ^ jw ^ r;
          res[o] = 0xFFFF0000u | (unsigned)r;           // o -> rep r, no partner
          res[r] = ((unsigned)o << 16) | (unsigned)r;   // r -> rep r, partner o
        }
      }
      m16 &= ~((lane == (i >> 4)) ? (1u << (i & 15)) : 0u);
    }
  };

#pragma unroll 1
  for (int i = 0; i < N_; i += 16) {
#pragma unroll
    for (int w = 0; w < 16; w++) {
      step(i + w, rr[w]);
      rr[w] = Eg[(size_t)(i + 16 + w) * 64 + lane];   // unconditional: tail reads land in perm region
    }
  }
  __syncthreads();
  for (int t = lane; t < N_; t += 64) {
    unsigned v = res[t];
    cluster[g0 + t] = (int)(v & 0xFFFFu);
    int p = (int)(v >> 16);
    partner[g0 + t] = (p == 0xFFFF) ? -1 : p;
  }
}

// ---------------------------------------------------------------- max pool
__global__ __launch_bounds__(256) void k_maxpool(
    const float* __restrict__ h1, const int* __restrict__ cluster, const int* __restrict__ partner,
    float* __restrict__ h1p, float* __restrict__ x2p, int* __restrict__ valid1,
    unsigned* __restrict__ vbits)
{
  int gi = blockIdx.x * 256 + threadIdx.x;
  int b = gi >> 10, i = gi & 1023;
  if (cluster[gi] == i) {
    int p = partner[gi];
    float s = 0.f;
#pragma unroll
    for (int q = 0; q < 16; q++) {
      float4 a = reinterpret_cast<const float4*>(h1)[gi * 16 + q];
      if (p >= 0) {
        float4 c = reinterpret_cast<const float4*>(h1)[(b * N_ + p) * 16 + q];
        a.x = fmaxf(a.x, c.x); a.y = fmaxf(a.y, c.y); a.z = fmaxf(a.z, c.z); a.w = fmaxf(a.w, c.w);
      }
      reinterpret_cast<float4*>(h1p)[gi * 16 + q] = a;
      s += a.x * a.x + a.y * a.y + a.z * a.z + a.w * a.w;
    }
    x2p[gi] = s; valid1[gi] = 1;
    atomicOr(&vbits[b * 32 + (i >> 5)], 1u << (i & 31));
  } else {
    float4 z = make_float4(0.f, 0.f, 0.f, 0.f);
#pragma unroll
    for (int q = 0; q < 16; q++) reinterpret_cast<float4*>(h1p)[gi * 16 + q] = z;
    x2p[gi] = 0.f; valid1[gi] = 0;
  }
}

// ---------------------------------------------------------------- global max + out MLP
__global__ __launch_bounds__(256) void k_final(
    const float* __restrict__ h2, const int* __restrict__ valid1,
    const float* __restrict__ o1W, const float* __restrict__ o1b,
    const float* __restrict__ o2W, const float* __restrict__ o2b,
    const float* __restrict__ o3W, const float* __restrict__ o3b,
    float* __restrict__ out)
{
  __shared__ float gm[4][64], g[64], l1[64], l2[32];
  int b = blockIdx.x, tid = threadIdx.x;
  int d = tid & 63, r = tid >> 6;
  float m = -INFF;
  for (int i = r; i < N_; i += 4) {
    if (valid1[b * N_ + i]) m = fmaxf(m, h2[(size_t)(b * N_ + i) * 64 + d]);
  }
  gm[r][d] = m;
  __syncthreads();
  if (tid < 64) g[d] = fmaxf(fmaxf(gm[0][d], gm[1][d]), fmaxf(gm[2][d], gm[3][d]));
  __syncthreads();
  if (tid < 64) {
    float a = o1b[tid];
    for (int c = 0; c < 64; c++) a += g[c] * o1W[c * 64 + tid];
    l1[tid] = elu_(a);
  }
  __syncthreads();
  if (tid < 32) {
    float a2 = o2b[tid];
    for (int c = 0; c < 64; c++) a2 += l1[c] * o2W[c * 32 + tid];
    l2[tid] = elu_(a2);
  }
  __syncthreads();
  if (tid < 2) {
    float a3 = o3b[tid];
    for (int c = 0; c < 32; c++) a3 += l2[c] * o3W[c * 2 + tid];
    out[b * 2 + tid] = a3;
  }
}

// ---------------------------------------------------------------- launch
extern "C" void kernel_launch(void* const* d_in, const int* in_sizes, int n_in,
                              void* d_out, int out_size, void* d_ws, size_t ws_size,
                              hipStream_t stream)
{
  const float* x    = (const float*)d_in[0];
  const float* nrm  = (const float*)d_in[1];
  const float* in1W = (const float*)d_in[2];  const float* in1b = (const float*)d_in[3];
  const float* in2W = (const float*)d_in[4];  const float* in2b = (const float*)d_in[5];
  const float* in3W = (const float*)d_in[6];  const float* in3b = (const float*)d_in[7];
  const float* c1aW = (const float*)d_in[8];  const float* c1ab = (const float*)d_in[9];
  const float* c1bW = (const float*)d_in[10]; const float* c1bb = (const float*)d_in[11];
  const float* c2aW = (const float*)d_in[12]; const float* c2ab = (const float*)d_in[13];
  const float* c2bW = (const float*)d_in[14]; const float* c2bb = (const float*)d_in[15];
  const float* o1W  = (const float*)d_in[16]; const float* o1b  = (const float*)d_in[17];
  const float* o2W  = (const float*)d_in[18]; const float* o2b  = (const float*)d_in[19];
  const float* o3W  = (const float*)d_in[20]; const float* o3b  = (const float*)d_in[21];

  // workspace layout. O_U is a union region with three disjoint-lifetime tenants:
  //   {pd 16MB + pix 8MB} (knn->merge)  |  {wb 12MB + vb 12MB} (uv->conv)  |  {cw 16MB} (wgt->sort)
  // h1p overlays h0; h2 overlays h1; E persists from elist1 through graclus (k_sort rewrites it
  // interleaved in place), rewritten linear at elist2. perm rebuilt per stage after its k_elist.
  constexpr size_t O_H0    = 0;                                   // h0 | h1p  (8 MB)
  constexpr size_t O_X2A   = O_H0    + (size_t)NN * 64 * 4;       // x2a | x2p
  constexpr size_t O_U     = O_X2A   + (size_t)NN * 4;            // union (24 MB)
  constexpr size_t O_K     = O_U     + (size_t)NN * NCH * 16 * 6; // K bitmask (4 MB)
  constexpr size_t O_KT    = O_K     + (size_t)NN * 32 * 4;       // KT bitmask (4 MB, contiguous after K)
  constexpr size_t O_H1    = O_KT    + (size_t)NN * 32 * 4;       // h1 | h2 (8 MB)
  constexpr size_t O_X2H   = O_H1    + (size_t)NN * 64 * 4;
  constexpr size_t O_IDG   = O_X2H   + (size_t)NN * 4;
  constexpr size_t O_ECNT  = O_IDG   + (size_t)NN * 4;
  constexpr size_t O_CLU   = O_ECNT  + (size_t)NN * 4;
  constexpr size_t O_PAR   = O_CLU   + (size_t)NN * 4;
  constexpr size_t O_VAL   = O_PAR   + (size_t)NN * 4;
  constexpr size_t O_VBITS = O_VAL   + (size_t)NN * 4;
  constexpr size_t O_E     = O_VBITS + (size_t)B_ * 32 * 4;       // edge list (8 MB)
  constexpr size_t O_PERM  = O_E     + (size_t)NN * ECAP * 2;     // degree perm (64 KB; also absorbs
  constexpr size_t TOTAL   = O_PERM  + (size_t)NN * 2;            //  graclus tail over-reads) ~57 MB
  if (ws_size < TOTAL) return;

  char* w = (char*)d_ws;
  float*          h0   = (float*)(w + O_H0);
  float*          x2a  = (float*)(w + O_X2A);
  float*          pdp  = (float*)(w + O_U);
  unsigned short* pip  = (unsigned short*)(w + O_U + (size_t)NN * NCH * 16 * 4);
  float*          wb   = (float*)(w + O_U);
  float*          vb   = (float*)(w + O_U + (size_t)NN * 96 * 4);
  unsigned*       cwt  = (unsigned*)(w + O_U);
  unsigned*       Kb   = (unsigned*)(w + O_K);
  unsigned*       KTb  = (unsigned*)(w + O_KT);
  float*          h1   = (float*)(w + O_H1);
  float*          x2h  = (float*)(w + O_X2H);
  float*          idg  = (float*)(w + O_IDG);
  int*            ecnt = (int*)(w + O_ECNT);
  int*            clu  = (int*)(w + O_CLU);
  int*            par  = (int*)(w + O_PAR);
  int*            val  = (int*)(w + O_VAL);
  unsigned*       vbits= (unsigned*)(w + O_VBITS);
  unsigned short* E    = (unsigned short*)(w + O_E);
  unsigned short* perm = (unsigned short*)(w + O_PERM);
  float* h1p = h0;
  float* x2p = x2a;
  float* h2  = h1;

  // ---- stage 1 (all nodes valid)
  k_input<<<NN / 256, 256, 0, stream>>>(x, nrm, in1W, in1b, in2W, in2b, in3W, in3b, h0, x2a);
  k_knn<<<B_ * 32, 256, 0, stream>>>((const float4*)h0, x2a, nullptr, nullptr, pdp, pip);
  hipMemsetAsync(KTb, 0, (size_t)NN * 32 * 4, stream);
  k_merge<<<NN / 64, 64, 0, stream>>>(pdp, pip, nullptr, Kb, KTb);
  k_elist<<<NN / 256, 256, 0, stream>>>(Kb, KTb, E, ecnt, idg);
  k_perm<<<B_, 256, 0, stream>>>(ecnt, perm);
  k_uv<<<NN / 256, 256, 0, stream>>>(h0, c1aW, c1ab, wb, vb);
  k_conv<<<NN / 64, 256, 0, stream>>>(wb, vb, E, ecnt, perm, c1bW, c1bb, h1, x2h);
  // ---- graclus + pool
  k_wgt<<<NN / 256, 256, 0, stream>>>(h1, x2h, idg, E, ecnt, cwt);
  k_sort<<<NN / 4, 256, 0, stream>>>(cwt, E, ecnt, (unsigned*)E);
  k_graclus<<<B_, 64, 0, stream>>>((const unsigned*)E, clu, par);
  hipMemsetAsync(vbits, 0, (size_t)B_ * 32 * 4, stream);
  k_maxpool<<<NN / 256, 256, 0, stream>>>(h1, clu, par, h1p, x2p, val, vbits);
  // ---- stage 2 (valid = cluster representatives; invalid rows have ecnt==0)
  k_knn<<<B_ * 32, 256, 0, stream>>>((const float4*)h1p, x2p, vbits, val, pdp, pip);
  hipMemsetAsync(Kb, 0, (size_t)NN * 32 * 4 * 2, stream);   // K and KT, contiguous
  k_merge<<<NN / 64, 64, 0, stream>>>(pdp, pip, val, Kb, KTb);
  k_elist<<<NN / 256, 256, 0, stream>>>(Kb, KTb, E, ecnt, nullptr);
  k_perm<<<B_, 256, 0, stream>>>(ecnt, perm);
  k_uv<<<NN / 256, 256, 0, stream>>>(h1p, c2aW, c2ab, wb, vb);
  k_conv<<<NN / 64, 256, 0, stream>>>(wb, vb, E, ecnt, perm, c2bW, c2bb, h2, nullptr);
  k_final<<<B_, 256, 0, stream>>>(h2, val, o1W, o1b, o2W, o2b, o3W, o3b, (float*)d_out);
}